// Round 11
// baseline (173.464 us; speedup 1.0000x reference)
//
#include <hip/hip_runtime.h>
#include <math.h>

// N=4, C=256, H=W=32, NH=2, HD=128, MAX_DIS=7, WS=15, WW=225, T=sqrt(128)
// out: [hw=1024][n=4][c=256] fp32
// Round-11: fc fused into scores. out = sum_g PV_g @ Wfc[:,g*128:+128]^T + bfc
// distributes over heads -> each scores block runs its 128-K FC GEMM on its
// own PV tile (B-frags read from the same LDS tile phase F already staged;
// A-frags are prep's sel-3 Wfc frags, kc = g*4..+3) and atomicAdds fp32 out.
// mfma_fc kernel + AG intermediate deleted.

typedef __attribute__((ext_vector_type(8))) short short8;
typedef __attribute__((ext_vector_type(4))) float floatx4;

__device__ __forceinline__ short f2bf(float f) {
    unsigned u = __float_as_uint(f);
    unsigned r = (u + 0x7fffu + ((u >> 16) & 1u)) >> 16;
    return (short)r;
}
__device__ __forceinline__ float bf2f(short s) {
    return __uint_as_float(((unsigned)(unsigned short)s) << 16);
}

// ---------------------------------------------------------------------------
// prep v3: pure fragment conversion (no GEMMs). 760 wave-units, 4/block,
// grid 190 x 256.
//  u [0,512)  : Wq/Wk/Wv/Wfc A-frags (sel = u>>7, dt/kc = u&127)
//  u [512,632): Wrel frags (g, wt, kc)
//  u [632,760): V_bias rows [g][128ch][256w] (w>=225 zero)
// ---------------------------------------------------------------------------
__global__ __launch_bounds__(256)
void prep(const float* __restrict__ Wq, const float* __restrict__ Wk,
          const float* __restrict__ Wv, const float* __restrict__ Wfc,
          const float* __restrict__ Wrel, const float* __restrict__ Vb,
          short* __restrict__ Whi, short* __restrict__ Wlo,
          short* __restrict__ Wrh, short* __restrict__ Wrl,
          short* __restrict__ Vbh, short* __restrict__ Vbl)
{
    const int tid = threadIdx.x;
    const int sub = tid >> 6, lane = tid & 63;
    const int n16 = lane & 15, quad = lane >> 4;
    const int u = blockIdx.x * 4 + sub;

    if (u < 512) {
        const int sel = u >> 7, rem = u & 127;
        const int dt = rem >> 3, kc = rem & 7;
        const float* W = (sel == 0 ? Wq : sel == 1 ? Wk : sel == 2 ? Wv : Wfc);
        const int d = dt * 16 + n16, cb = kc * 32 + quad * 8;
        float4 w0 = *(const float4*)&W[(long)d * 256 + cb];
        float4 w1 = *(const float4*)&W[(long)d * 256 + cb + 4];
        float f[8] = {w0.x, w0.y, w0.z, w0.w, w1.x, w1.y, w1.z, w1.w};
        short8 h8, l8;
#pragma unroll
        for (int j = 0; j < 8; ++j) {
            short hb = f2bf(f[j]);
            h8[j] = hb;
            l8[j] = f2bf(f[j] - bf2f(hb));
        }
        long off = (long)sel * 65536 + (((long)(dt * 8 + kc) * 64) + lane) * 8;
        *(short8*)(Whi + off) = h8;
        *(short8*)(Wlo + off) = l8;
    } else if (u < 632) {
        const int t = u - 512;
        const int g = t / 60, r = t - g * 60;
        const int wt = r >> 2, kc = r & 3;
        const int w = wt * 16 + n16;         // valid < 225
        const int cb = kc * 32 + quad * 8;
        float f[8] = {0.f, 0.f, 0.f, 0.f, 0.f, 0.f, 0.f, 0.f};
        if (w < 225) {
            float4 w0 = *(const float4*)&Wrel[(long)(g * 225 + w) * 128 + cb];
            float4 w1 = *(const float4*)&Wrel[(long)(g * 225 + w) * 128 + cb + 4];
            f[0] = w0.x; f[1] = w0.y; f[2] = w0.z; f[3] = w0.w;
            f[4] = w1.x; f[5] = w1.y; f[6] = w1.z; f[7] = w1.w;
        }
        short8 h8, l8;
#pragma unroll
        for (int j = 0; j < 8; ++j) {
            short hb = f2bf(f[j]);
            h8[j] = hb;
            l8[j] = f2bf(f[j] - bf2f(hb));
        }
        long off = (long)g * 30720 + (((long)(wt * 4 + kc) * 64) + lane) * 8;
        *(short8*)(Wrh + off) = h8;
        *(short8*)(Wrl + off) = l8;
    } else {
        const int t = u - 632;
        const int g = t >> 6, r = t & 63;
        const int dt = r >> 3, wk = r & 7;
        const int ch = dt * 16 + n16;
        const int w0 = wk * 32 + quad * 8;
        float f[8];
#pragma unroll
        for (int j = 0; j < 8; ++j) {
            int w = w0 + j;
            f[j] = (w < 225) ? Vb[(long)(g * 128 + ch) * 225 + w] : 0.f;
        }
        short8 h8, l8;
#pragma unroll
        for (int j = 0; j < 8; ++j) {
            short hb = f2bf(f[j]);
            h8[j] = hb;
            l8[j] = f2bf(f[j] - bf2f(hb));
        }
        long off = (((long)(g * 128 + ch)) << 8) + w0;
        *(short8*)(Vbh + off) = h8;
        *(short8*)(Vbl + off) = l8;
    }
}

// ---------------------------------------------------------------------------
// mfma_proj v8 (unchanged): pre-converted A-frags, raw-input LDS staging.
// grid (64 mt16, 12 z); sel = z>>2: 0=q, 1=k, 2=v.
// ---------------------------------------------------------------------------
__global__ __launch_bounds__(256)
void mfma_proj(const float* __restrict__ q, const float* __restrict__ k,
               const float* __restrict__ v,
               const short* __restrict__ Whi, const short* __restrict__ Wlo,
               const float* __restrict__ bq, const float* __restrict__ bk,
               const float* __restrict__ bv,
               short* __restrict__ qhi, short* __restrict__ qlo,
               short* __restrict__ khi, short* __restrict__ klo,
               short* __restrict__ vhi, short* __restrict__ vlo)
{
    __shared__ float st[256 * 17];       // staging [c 256][m 16 +1]; aliased as tile[16][257]
    const int tid = threadIdx.x;
    const int wave = tid >> 6, lane = tid & 63;
    const int n16 = lane & 15, quad = lane >> 4;
    const int mt16 = blockIdx.x, z = blockIdx.y;
    const int sel = z >> 2, batch = z & 3;

    const float* X = (sel == 0 ? q : sel == 1 ? k : v) + ((long)batch << 18);

    // ---- stage X tile: thread tid = channel c, 16 m's ----
    {
        const float* src = X + ((long)tid << 10) + mt16 * 16;
        float4 a0 = *(const float4*)(src);
        float4 a1 = *(const float4*)(src + 4);
        float4 a2 = *(const float4*)(src + 8);
        float4 a3 = *(const float4*)(src + 12);
        float* d = &st[tid * 17];
        d[0] = a0.x; d[1] = a0.y; d[2] = a0.z; d[3] = a0.w;
        d[4] = a1.x; d[5] = a1.y; d[6] = a1.z; d[7] = a1.w;
        d[8] = a2.x; d[9] = a2.y; d[10] = a2.z; d[11] = a2.w;
        d[12] = a3.x; d[13] = a3.y; d[14] = a3.z; d[15] = a3.w;
    }

    const float* bias = (sel == 0 ? bq : sel == 1 ? bk : bv);
    float bbv[4][4];
#pragma unroll
    for (int i = 0; i < 4; ++i) {
        float4 b4 = *(const float4*)&bias[(wave * 4 + i) * 16 + quad * 4];
        bbv[i][0] = b4.x; bbv[i][1] = b4.y; bbv[i][2] = b4.z; bbv[i][3] = b4.w;
    }
    __syncthreads();

    floatx4 acc[4] = {{0.f,0.f,0.f,0.f},{0.f,0.f,0.f,0.f},
                      {0.f,0.f,0.f,0.f},{0.f,0.f,0.f,0.f}};
    const long abase = (long)sel * 65536 + (long)lane * 8;
#pragma unroll
    for (int kc = 0; kc < 8; ++kc) {
        short8 bh, bl;
        const float* col = &st[(kc * 32 + quad * 8) * 17 + n16];
#pragma unroll
        for (int j = 0; j < 8; ++j) {
            float f = col[j * 17];
            short hb = f2bf(f);
            bh[j] = hb;
            bl[j] = f2bf(f - bf2f(hb));
        }
#pragma unroll
        for (int i = 0; i < 4; ++i) {
            const int dt = wave * 4 + i;
            short8 ahi = *(const short8*)(Whi + abase + (long)(dt * 8 + kc) * 512);
            short8 alo = *(const short8*)(Wlo + abase + (long)(dt * 8 + kc) * 512);
            acc[i] = __builtin_amdgcn_mfma_f32_16x16x32_bf16(ahi, bh, acc[i], 0, 0, 0);
            acc[i] = __builtin_amdgcn_mfma_f32_16x16x32_bf16(ahi, bl, acc[i], 0, 0, 0);
            acc[i] = __builtin_amdgcn_mfma_f32_16x16x32_bf16(alo, bh, acc[i], 0, 0, 0);
        }
    }

    // stage D[16 m][256 c] (alias st)
    __syncthreads();                      // st B-frag reads done
    float* tile = st;
#pragma unroll
    for (int i = 0; i < 4; ++i) {
        const int dt = wave * 4 + i;
#pragma unroll
        for (int r = 0; r < 4; ++r)
            tile[n16 * 257 + dt * 16 + quad * 4 + r] = acc[i][r] + bbv[i][r];
    }
    __syncthreads();

    if (sel == 2) {
        // coalesced transposed V write: thread = channel
        const int gg = tid >> 7, chp = tid & 127;
        const int yq = mt16 >> 1, xb = (mt16 & 1) * 16;
        short8 h0, h1, l0, l1;
#pragma unroll
        for (int j = 0; j < 8; ++j) {
            float f0 = tile[j * 257 + tid];
            float f1 = tile[(j + 8) * 257 + tid];
            short hb0 = f2bf(f0), hb1 = f2bf(f1);
            h0[j] = hb0; l0[j] = f2bf(f0 - bf2f(hb0));
            h1[j] = hb1; l1[j] = f2bf(f1 - bf2f(hb1));
        }
        long o = ((long)((batch * 2 + gg) * 128 + chp) * 32 + yq) * 48 + 8 + xb;
        *(short8*)(vhi + o) = h0;
        *(short8*)(vhi + o + 8) = h1;
        *(short8*)(vlo + o) = l0;
        *(short8*)(vlo + o + 8) = l1;
        // zero x-pads: this block zeroes (row = mt16>>1, side = mt16&1), all 256 ch
        const int prow = mt16 >> 1, side = mt16 & 1;
        long po = ((long)((batch * 2 + gg) * 128 + chp) * 32 + prow) * 48 + side * 40;
        short8 zz = {0,0,0,0,0,0,0,0};
        *(short8*)(vhi + po) = zz;
        *(short8*)(vlo + po) = zz;
        return;
    }

    const float scale = (sel == 1) ? 0.08838834764831845f : 1.0f;
    const int m_l = tid >> 4, c16 = (tid & 15) * 16;
    const int m = mt16 * 16 + m_l;
    short* oh = sel ? khi : qhi;
    short* ol = sel ? klo : qlo;
#pragma unroll
    for (int half = 0; half < 2; ++half) {
        const int cg = c16 + half * 8;
        short8 h8, l8;
#pragma unroll
        for (int j = 0; j < 8; ++j) {
            float f = tile[m_l * 257 + cg + j] * scale;
            short hb = f2bf(f);
            h8[j] = hb;
            l8[j] = f2bf(f - bf2f(hb));
        }
        const int g = cg >> 7, ch = cg & 127;
        const long base = (((long)(batch * 2 + g) << 10) + m) * 128 + ch;
        *(short8*)(oh + base) = h8;
        *(short8*)(ol + base) = l8;
    }
}

// ---------------------------------------------------------------------------
// scores_pv (round-19): round-10 kernel + FC fused into phase F.
// 512 px-tiles x 512 threads (8 waves), XCD swizzle bz = lin&7.
// Phase F: stage PV tile[16][133] -> per wave build 4 B-frag hi/lo from the
// tile (same elements the old AG path stored), MFMA against prep's sel-3
// Wfc A-frags (kc = g*4..+3 = this head's 128-ch K), atomicAdd fp32 out
// (+bfc from the g==0 block).
// ---------------------------------------------------------------------------
__global__ __launch_bounds__(512)
void scores_pv(const short* __restrict__ qhi, const short* __restrict__ qlo,
               const short* __restrict__ khi, const short* __restrict__ klo,
               const short* __restrict__ Wrh, const short* __restrict__ Wrl,
               const float* __restrict__ brel,
               const short* __restrict__ vhi, const short* __restrict__ vlo,
               const short* __restrict__ Vbh, const short* __restrict__ Vbl,
               const short* __restrict__ Whi, const short* __restrict__ Wlo,
               const float* __restrict__ bfc, float* __restrict__ out)
{
    __shared__ __align__(16) float qk[16 * 241];   // 15.4 KB; aliased as tile[16][133] in F
    __shared__ __align__(16) short pah[16 * 264];  // 8.25 KB  P hi (rows padded to 264)
    __shared__ __align__(16) short pal[16 * 264];  // 8.25 KB  P lo
    __shared__ float invl[16];

    const int tid = threadIdx.x;
    const int wave = tid >> 6, lane = tid & 63;     // wave 0..7
    const int lin = blockIdx.x;
    const int bz  = lin & 7;         // XCD-resident head/batch
    const int yy  = lin >> 3;        // 0..63
    const int y   = yy >> 1;
    const int xt  = yy & 1;
    const int g = bz & 1;
    const int x0 = xt * 16;

    const int n16 = lane & 15, quad = lane >> 4;
    const long qbase = (((long)bz << 10) + y * 32 + x0 + n16) * 128 + quad * 8;
    short8 a_hi[4], a_lo[4];
#pragma unroll
    for (int ch = 0; ch < 4; ++ch) {
        a_hi[ch] = *(const short8*)(qhi + qbase + ch * 32);
        a_lo[ch] = *(const short8*)(qlo + qbase + ch * 32);
    }

    // ---- phase R: rel logits (15 wt over 8 waves) ----
    for (int wt = wave; wt < 15; wt += 8) {
        const short* Ah = Wrh + (long)g * 30720 + ((long)(wt * 4) * 64 + lane) * 8;
        const short* Al = Wrl + (long)g * 30720 + ((long)(wt * 4) * 64 + lane) * 8;
        floatx4 racc = {0.f, 0.f, 0.f, 0.f};
#pragma unroll
        for (int kc = 0; kc < 4; ++kc) {
            short8 whh = *(const short8*)(Ah + kc * 512);
            short8 wll = *(const short8*)(Al + kc * 512);
            racc = __builtin_amdgcn_mfma_f32_16x16x32_bf16(whh, a_hi[kc], racc, 0, 0, 0);
            racc = __builtin_amdgcn_mfma_f32_16x16x32_bf16(whh, a_lo[kc], racc, 0, 0, 0);
            racc = __builtin_amdgcn_mfma_f32_16x16x32_bf16(wll, a_hi[kc], racc, 0, 0, 0);
        }
#pragma unroll
        for (int r = 0; r < 4; ++r) {
            int w = wt * 16 + quad * 4 + r;
            if (w < 225) {
                int dy = w / 15, dx = w - dy * 15;
                qk[n16 * 241 + dy * 16 + dx] = racc[r] + brel[g * 225 + w];
            }
        }
    }
    __syncthreads();

    // ---- phase M: mask invalid neighbors and pad slots ----
    for (int e = tid; e < 16 * 241; e += 512) {
        int px = e / 241, idx = e - px * 241;
        int dy = idx >> 4, dx = idx & 15;
        int hy = y + dy - 7, hx = x0 + px + dx - 7;
        bool valid = (dx < 15) && (dy < 15) &&
                     (hy >= 0) && (hy < 32) && (hx >= 0) && (hx < 32);
        if (!valid) qk[e] = -1e8f;
    }
    __syncthreads();

    // ---- phase B: band QK^T (15 dy over 8 waves) ----
    for (int dy = wave; dy < 15; dy += 8) {
        const int ky = y + dy - 7;
        if (ky < 0 || ky > 31) continue;
#pragma unroll
        for (int kxt = 0; kxt < 2; ++kxt) {
            const int kxg = x0 - 8 + kxt * 16 + n16;
            const long kb = (((long)bz << 10) + ky * 32 + kxg) * 128 + quad * 8;
            floatx4 acc = {0.f, 0.f, 0.f, 0.f};
#pragma unroll
            for (int ch = 0; ch < 4; ++ch) {
                short8 b_hi = *(const short8*)(khi + kb + ch * 32);
                short8 b_lo = *(const short8*)(klo + kb + ch * 32);
                acc = __builtin_amdgcn_mfma_f32_16x16x32_bf16(a_hi[ch], b_hi, acc, 0, 0, 0);
                acc = __builtin_amdgcn_mfma_f32_16x16x32_bf16(a_hi[ch], b_lo, acc, 0, 0, 0);
                acc = __builtin_amdgcn_mfma_f32_16x16x32_bf16(a_lo[ch], b_hi, acc, 0, 0, 0);
            }
            if (kxg >= 0 && kxg < 32) {
#pragma unroll
                for (int r = 0; r < 4; ++r) {
                    int m = quad * 4 + r;
                    int dx = kxg - (x0 + m) + 7;
                    if (dx >= 0 && dx < 15) {
                        int s = m * 241 + dy * 16 + dx;
                        qk[s] = qk[s] + acc[r];
                    }
                }
            }
        }
    }
    __syncthreads();

    // ---- softmax: 32 lanes per px row ----
    {
        int px = tid >> 5, s = tid & 31;
        float mx = -3.0e38f;
        for (int w = s; w < 240; w += 32) mx = fmaxf(mx, qk[px * 241 + w]);
#pragma unroll
        for (int msk = 16; msk; msk >>= 1) mx = fmaxf(mx, __shfl_xor(mx, msk));
        float sum = 0.f;
        for (int w = s; w < 240; w += 32) {
            float p = __expf(qk[px * 241 + w] - mx);
            qk[px * 241 + w] = p;
            sum += p;
        }
#pragma unroll
        for (int msk = 16; msk; msk >>= 1) sum += __shfl_xor(sum, msk);
        if (s == 0) invl[px] = 1.0f / sum;
    }
    __syncthreads();

    // ---- phase T: normalize + bf16 hi/lo into pah/pal (w >= 225 -> 0) ----
    for (int e = tid; e < 4096; e += 512) {
        int px = e >> 8, w = e & 255;
        float p = 0.f;
        if (w < 225) {
            int dy2 = w / 15, dx2 = w - dy2 * 15;
            p = qk[px * 241 + dy2 * 16 + dx2] * invl[px];
        }
        short hb = f2bf(p);
        pah[px * 264 + w] = hb;
        pal[px * 264 + w] = f2bf(p - bf2f(hb));
    }
    __syncthreads();
    // qk is dead from here on; tile aliases it in phase F.

    // ---- phases A+V: MFMA accumulation, 1 ch-tile per wave (8 tiles) ----
    floatx4 acc = {0.f, 0.f, 0.f, 0.f};
    const int ch0 = wave * 16;

    // (A) bias GEMM: P[16 x 225] x Vbh[225 x 128], 8 k-chunks of 32
#pragma unroll
    for (int wk = 0; wk < 8; ++wk) {
        short8 pa_h = *(const short8*)&pah[n16 * 264 + wk * 32 + quad * 8];
        short8 pa_l = *(const short8*)&pal[n16 * 264 + wk * 32 + quad * 8];
        const long vb0 = (((long)(g * 128 + ch0 + n16)) << 8) + wk * 32 + quad * 8;
        short8 b0h = *(const short8*)(Vbh + vb0);
        short8 b0l = *(const short8*)(Vbl + vb0);
        acc = __builtin_amdgcn_mfma_f32_16x16x32_bf16(pa_h, b0h, acc, 0, 0, 0);
        acc = __builtin_amdgcn_mfma_f32_16x16x32_bf16(pa_h, b0l, acc, 0, 0, 0);
        acc = __builtin_amdgcn_mfma_f32_16x16x32_bf16(pa_l, b0h, acc, 0, 0, 0);
    }

    // (V) banded GEMM per dy: P'[px][k] = P[px][dy*15 + k-px-1], k-cols x0-8..x0+23
    for (int dy = 0; dy < 15; ++dy) {
        const int ky = y + dy - 7;
        if (ky < 0 || ky > 31) continue;    // those P rows are exactly 0
        short8 bnd_h, bnd_l;
        const int rowoff = n16 * 264 + dy * 15 - n16 - 1;
#pragma unroll
        for (int j = 0; j < 8; ++j) {
            int kk = quad * 8 + j;
            int dx = kk - n16 - 1;
            bool valid = (unsigned)dx < 15u;
            int idx = valid ? (rowoff + kk) : 0;
            short vh = pah[idx];
            short vl = pal[idx];
            bnd_h[j] = valid ? vh : (short)0;
            bnd_l[j] = valid ? vl : (short)0;
        }
        const long v0o = (((long)((bz * 128 + ch0 + n16)) * 32 + ky)) * 48 + x0 + quad * 8;
        short8 v0h = *(const short8*)(vhi + v0o);
        short8 v0l = *(const short8*)(vlo + v0o);
        acc = __builtin_amdgcn_mfma_f32_16x16x32_bf16(bnd_h, v0h, acc, 0, 0, 0);
        acc = __builtin_amdgcn_mfma_f32_16x16x32_bf16(bnd_h, v0l, acc, 0, 0, 0);
        acc = __builtin_amdgcn_mfma_f32_16x16x32_bf16(bnd_l, v0h, acc, 0, 0, 0);
    }

    // ---- phase F: stage PV tile [16 px][128 ch], then fused FC GEMM ----
    float* tile = qk;                    // [16][133]
    {
        const int cb = ch0 + n16;
#pragma unroll
        for (int r = 0; r < 4; ++r)
            tile[(quad * 4 + r) * 133 + cb] = acc[r];
    }
    __syncthreads();

    // build 4 B-frag hi/lo pairs (this g's 128-ch K, slices of 32)
    short8 fbh[4], fbl[4];
#pragma unroll
    for (int s = 0; s < 4; ++s) {
#pragma unroll
        for (int j = 0; j < 8; ++j) {
            float f = tile[n16 * 133 + s * 32 + quad * 8 + j];
            short hb = f2bf(f);
            fbh[s][j] = hb;
            fbl[s][j] = f2bf(f - bf2f(hb));
        }
    }

    // FC: out[px][d] += sum_ch PV[px][ch] * Wfc[d][g*128+ch]; 2 d-tiles/wave
    const int n = bz >> 1;
    const long wfcbase = (long)3 * 65536 + (long)lane * 8;
#pragma unroll
    for (int t = 0; t < 2; ++t) {
        const int dt = wave * 2 + t;
        floatx4 fa = {0.f, 0.f, 0.f, 0.f};
#pragma unroll
        for (int s = 0; s < 4; ++s) {
            const int kc = g * 4 + s;
            short8 ahi = *(const short8*)(Whi + wfcbase + (long)(dt * 8 + kc) * 512);
            short8 alo = *(const short8*)(Wlo + wfcbase + (long)(dt * 8 + kc) * 512);
            fa = __builtin_amdgcn_mfma_f32_16x16x32_bf16(ahi, fbh[s], fa, 0, 0, 0);
            fa = __builtin_amdgcn_mfma_f32_16x16x32_bf16(ahi, fbl[s], fa, 0, 0, 0);
            fa = __builtin_amdgcn_mfma_f32_16x16x32_bf16(alo, fbh[s], fa, 0, 0, 0);
        }
        // D: col = n16 = px, row = quad*4+r within d-tile
#pragma unroll
        for (int r = 0; r < 4; ++r) {
            const int d = dt * 16 + quad * 4 + r;
            const float add = fa[r] + ((g == 0) ? bfc[d] : 0.f);
            long o = ((long)(y * 32 + x0 + n16) * 4 + n) * 256 + d;
            atomicAdd(&out[o], add);
        }
    }
}

// ---------------------------------------------------------------------------
// ws floats:
//   vhi@2097152 (786432 fl as shorts) vlo@2883584
//   Vbh@4718592 (32768 fl) Vbl@4751360
//   qhi@6561792 qlo@7086080 khi@7610368 klo@8134656 (524288 each)
//   Whi@11804672 (131072, 4 sels) Wlo@11935744
//   Wrh@13115392 (30720) Wrl@13146112
// ---------------------------------------------------------------------------
extern "C" void kernel_launch(void* const* d_in, const int* in_sizes, int n_in,
                              void* d_out, int out_size, void* d_ws, size_t ws_size,
                              hipStream_t stream)
{
    const float* q    = (const float*)d_in[0];
    const float* k    = (const float*)d_in[1];
    const float* v    = (const float*)d_in[2];
    const float* Wq   = (const float*)d_in[3];
    const float* bq   = (const float*)d_in[4];
    const float* Wk   = (const float*)d_in[5];
    const float* bk   = (const float*)d_in[6];
    const float* Wv   = (const float*)d_in[7];
    const float* bv   = (const float*)d_in[8];
    const float* Wrel = (const float*)d_in[9];
    const float* brel = (const float*)d_in[10];
    const float* Vb   = (const float*)d_in[11];
    const float* Wfc  = (const float*)d_in[12];
    const float* bfc  = (const float*)d_in[13];
    float* out = (float*)d_out;

    float* ws   = (float*)d_ws;
    short* vhi  = (short*)(ws + 2097152);
    short* vlo  = (short*)(ws + 2883584);
    short* Vbh  = (short*)(ws + 4718592);
    short* Vbl  = (short*)(ws + 4751360);
    short* qhi  = (short*)(ws + 6561792);
    short* qlo  = (short*)(ws + 7086080);
    short* khi  = (short*)(ws + 7610368);
    short* klo  = (short*)(ws + 8134656);
    short* Whi  = (short*)(ws + 11804672);
    short* Wlo  = (short*)(ws + 11935744);
    short* Wrh  = (short*)(ws + 13115392);
    short* Wrl  = (short*)(ws + 13146112);

    // out accumulates atomically (2 head-blocks per element) -> zero first
    hipMemsetAsync(d_out, 0, out_size, stream);

    // fragment conversion: Wq/Wk/Wv/Wfc A-frags, Wrel, V_bias rows
    prep<<<dim3(190), dim3(256), 0, stream>>>(Wq, Wk, Wv, Wfc, Wrel, Vb,
                                              Whi, Wlo, Wrh, Wrl, Vbh, Vbl);

    // QKV projections (pre-converted A-frags): 768 blocks
    mfma_proj<<<dim3(64, 12), dim3(256), 0, stream>>>(q, k, v, Whi, Wlo,
                                                      bq, bk, bv,
                                                      qhi, qlo, khi, klo,
                                                      vhi, vlo);

    // rel + scores + softmax + MFMA PV + fused FC -> out: 512 x 512 threads
    scores_pv<<<dim3(512), dim3(512), 0, stream>>>(qhi, qlo, khi, klo,
                                                   Wrh, Wrl, brel,
                                                   vhi, vlo, Vbh, Vbl,
                                                   Whi, Wlo, bfc, out);
}

// Round 12
// 158.804 us; speedup vs baseline: 1.0923x; 1.0923x over previous
//
#include <hip/hip_runtime.h>
#include <math.h>

// N=4, C=256, H=W=32, NH=2, HD=128, MAX_DIS=7, WS=15, WW=225, T=sqrt(128)
// out: [hw=1024][n=4][c=256] fp32
// Round-12: revert round-11 fc-fusion (atomics -> 32MB RMW traffic, -18us).
// Round-10 architecture + scores_pv at 1024 threads/16 waves: per-wave
// serial work halved again (the only lever that has moved scores: r2 vs r7).

typedef __attribute__((ext_vector_type(8))) short short8;
typedef __attribute__((ext_vector_type(4))) float floatx4;

__device__ __forceinline__ short f2bf(float f) {
    unsigned u = __float_as_uint(f);
    unsigned r = (u + 0x7fffu + ((u >> 16) & 1u)) >> 16;
    return (short)r;
}
__device__ __forceinline__ float bf2f(short s) {
    return __uint_as_float(((unsigned)(unsigned short)s) << 16);
}

// ---------------------------------------------------------------------------
// prep v3: pure fragment conversion (no GEMMs). 760 wave-units, 4/block,
// grid 190 x 256.
// ---------------------------------------------------------------------------
__global__ __launch_bounds__(256)
void prep(const float* __restrict__ Wq, const float* __restrict__ Wk,
          const float* __restrict__ Wv, const float* __restrict__ Wfc,
          const float* __restrict__ Wrel, const float* __restrict__ Vb,
          short* __restrict__ Whi, short* __restrict__ Wlo,
          short* __restrict__ Wrh, short* __restrict__ Wrl,
          short* __restrict__ Vbh, short* __restrict__ Vbl)
{
    const int tid = threadIdx.x;
    const int sub = tid >> 6, lane = tid & 63;
    const int n16 = lane & 15, quad = lane >> 4;
    const int u = blockIdx.x * 4 + sub;

    if (u < 512) {
        const int sel = u >> 7, rem = u & 127;
        const int dt = rem >> 3, kc = rem & 7;
        const float* W = (sel == 0 ? Wq : sel == 1 ? Wk : sel == 2 ? Wv : Wfc);
        const int d = dt * 16 + n16, cb = kc * 32 + quad * 8;
        float4 w0 = *(const float4*)&W[(long)d * 256 + cb];
        float4 w1 = *(const float4*)&W[(long)d * 256 + cb + 4];
        float f[8] = {w0.x, w0.y, w0.z, w0.w, w1.x, w1.y, w1.z, w1.w};
        short8 h8, l8;
#pragma unroll
        for (int j = 0; j < 8; ++j) {
            short hb = f2bf(f[j]);
            h8[j] = hb;
            l8[j] = f2bf(f[j] - bf2f(hb));
        }
        long off = (long)sel * 65536 + (((long)(dt * 8 + kc) * 64) + lane) * 8;
        *(short8*)(Whi + off) = h8;
        *(short8*)(Wlo + off) = l8;
    } else if (u < 632) {
        const int t = u - 512;
        const int g = t / 60, r = t - g * 60;
        const int wt = r >> 2, kc = r & 3;
        const int w = wt * 16 + n16;         // valid < 225
        const int cb = kc * 32 + quad * 8;
        float f[8] = {0.f, 0.f, 0.f, 0.f, 0.f, 0.f, 0.f, 0.f};
        if (w < 225) {
            float4 w0 = *(const float4*)&Wrel[(long)(g * 225 + w) * 128 + cb];
            float4 w1 = *(const float4*)&Wrel[(long)(g * 225 + w) * 128 + cb + 4];
            f[0] = w0.x; f[1] = w0.y; f[2] = w0.z; f[3] = w0.w;
            f[4] = w1.x; f[5] = w1.y; f[6] = w1.z; f[7] = w1.w;
        }
        short8 h8, l8;
#pragma unroll
        for (int j = 0; j < 8; ++j) {
            short hb = f2bf(f[j]);
            h8[j] = hb;
            l8[j] = f2bf(f[j] - bf2f(hb));
        }
        long off = (long)g * 30720 + (((long)(wt * 4 + kc) * 64) + lane) * 8;
        *(short8*)(Wrh + off) = h8;
        *(short8*)(Wrl + off) = l8;
    } else {
        const int t = u - 632;
        const int g = t >> 6, r = t & 63;
        const int dt = r >> 3, wk = r & 7;
        const int ch = dt * 16 + n16;
        const int w0 = wk * 32 + quad * 8;
        float f[8];
#pragma unroll
        for (int j = 0; j < 8; ++j) {
            int w = w0 + j;
            f[j] = (w < 225) ? Vb[(long)(g * 128 + ch) * 225 + w] : 0.f;
        }
        short8 h8, l8;
#pragma unroll
        for (int j = 0; j < 8; ++j) {
            short hb = f2bf(f[j]);
            h8[j] = hb;
            l8[j] = f2bf(f[j] - bf2f(hb));
        }
        long off = (((long)(g * 128 + ch)) << 8) + w0;
        *(short8*)(Vbh + off) = h8;
        *(short8*)(Vbl + off) = l8;
    }
}

// ---------------------------------------------------------------------------
// mfma_proj v8 (round-10 verbatim): pre-converted A-frags, LDS staging.
// grid (64 mt16, 12 z); sel = z>>2: 0=q, 1=k, 2=v.
// ---------------------------------------------------------------------------
__global__ __launch_bounds__(256)
void mfma_proj(const float* __restrict__ q, const float* __restrict__ k,
               const float* __restrict__ v,
               const short* __restrict__ Whi, const short* __restrict__ Wlo,
               const float* __restrict__ bq, const float* __restrict__ bk,
               const float* __restrict__ bv,
               short* __restrict__ qhi, short* __restrict__ qlo,
               short* __restrict__ khi, short* __restrict__ klo,
               short* __restrict__ vhi, short* __restrict__ vlo)
{
    __shared__ float st[256 * 17];
    const int tid = threadIdx.x;
    const int wave = tid >> 6, lane = tid & 63;
    const int n16 = lane & 15, quad = lane >> 4;
    const int mt16 = blockIdx.x, z = blockIdx.y;
    const int sel = z >> 2, batch = z & 3;

    const float* X = (sel == 0 ? q : sel == 1 ? k : v) + ((long)batch << 18);

    {
        const float* src = X + ((long)tid << 10) + mt16 * 16;
        float4 a0 = *(const float4*)(src);
        float4 a1 = *(const float4*)(src + 4);
        float4 a2 = *(const float4*)(src + 8);
        float4 a3 = *(const float4*)(src + 12);
        float* d = &st[tid * 17];
        d[0] = a0.x; d[1] = a0.y; d[2] = a0.z; d[3] = a0.w;
        d[4] = a1.x; d[5] = a1.y; d[6] = a1.z; d[7] = a1.w;
        d[8] = a2.x; d[9] = a2.y; d[10] = a2.z; d[11] = a2.w;
        d[12] = a3.x; d[13] = a3.y; d[14] = a3.z; d[15] = a3.w;
    }

    const float* bias = (sel == 0 ? bq : sel == 1 ? bk : bv);
    float bbv[4][4];
#pragma unroll
    for (int i = 0; i < 4; ++i) {
        float4 b4 = *(const float4*)&bias[(wave * 4 + i) * 16 + quad * 4];
        bbv[i][0] = b4.x; bbv[i][1] = b4.y; bbv[i][2] = b4.z; bbv[i][3] = b4.w;
    }
    __syncthreads();

    floatx4 acc[4] = {{0.f,0.f,0.f,0.f},{0.f,0.f,0.f,0.f},
                      {0.f,0.f,0.f,0.f},{0.f,0.f,0.f,0.f}};
    const long abase = (long)sel * 65536 + (long)lane * 8;
#pragma unroll
    for (int kc = 0; kc < 8; ++kc) {
        short8 bh, bl;
        const float* col = &st[(kc * 32 + quad * 8) * 17 + n16];
#pragma unroll
        for (int j = 0; j < 8; ++j) {
            float f = col[j * 17];
            short hb = f2bf(f);
            bh[j] = hb;
            bl[j] = f2bf(f - bf2f(hb));
        }
#pragma unroll
        for (int i = 0; i < 4; ++i) {
            const int dt = wave * 4 + i;
            short8 ahi = *(const short8*)(Whi + abase + (long)(dt * 8 + kc) * 512);
            short8 alo = *(const short8*)(Wlo + abase + (long)(dt * 8 + kc) * 512);
            acc[i] = __builtin_amdgcn_mfma_f32_16x16x32_bf16(ahi, bh, acc[i], 0, 0, 0);
            acc[i] = __builtin_amdgcn_mfma_f32_16x16x32_bf16(ahi, bl, acc[i], 0, 0, 0);
            acc[i] = __builtin_amdgcn_mfma_f32_16x16x32_bf16(alo, bh, acc[i], 0, 0, 0);
        }
    }

    __syncthreads();
    float* tile = st;
#pragma unroll
    for (int i = 0; i < 4; ++i) {
        const int dt = wave * 4 + i;
#pragma unroll
        for (int r = 0; r < 4; ++r)
            tile[n16 * 257 + dt * 16 + quad * 4 + r] = acc[i][r] + bbv[i][r];
    }
    __syncthreads();

    if (sel == 2) {
        const int gg = tid >> 7, chp = tid & 127;
        const int yq = mt16 >> 1, xb = (mt16 & 1) * 16;
        short8 h0, h1, l0, l1;
#pragma unroll
        for (int j = 0; j < 8; ++j) {
            float f0 = tile[j * 257 + tid];
            float f1 = tile[(j + 8) * 257 + tid];
            short hb0 = f2bf(f0), hb1 = f2bf(f1);
            h0[j] = hb0; l0[j] = f2bf(f0 - bf2f(hb0));
            h1[j] = hb1; l1[j] = f2bf(f1 - bf2f(hb1));
        }
        long o = ((long)((batch * 2 + gg) * 128 + chp) * 32 + yq) * 48 + 8 + xb;
        *(short8*)(vhi + o) = h0;
        *(short8*)(vhi + o + 8) = h1;
        *(short8*)(vlo + o) = l0;
        *(short8*)(vlo + o + 8) = l1;
        const int prow = mt16 >> 1, side = mt16 & 1;
        long po = ((long)((batch * 2 + gg) * 128 + chp) * 32 + prow) * 48 + side * 40;
        short8 zz = {0,0,0,0,0,0,0,0};
        *(short8*)(vhi + po) = zz;
        *(short8*)(vlo + po) = zz;
        return;
    }

    const float scale = (sel == 1) ? 0.08838834764831845f : 1.0f;
    const int m_l = tid >> 4, c16 = (tid & 15) * 16;
    const int m = mt16 * 16 + m_l;
    short* oh = sel ? khi : qhi;
    short* ol = sel ? klo : qlo;
#pragma unroll
    for (int half = 0; half < 2; ++half) {
        const int cg = c16 + half * 8;
        short8 h8, l8;
#pragma unroll
        for (int j = 0; j < 8; ++j) {
            float f = tile[m_l * 257 + cg + j] * scale;
            short hb = f2bf(f);
            h8[j] = hb;
            l8[j] = f2bf(f - bf2f(hb));
        }
        const int g = cg >> 7, ch = cg & 127;
        const long base = (((long)(batch * 2 + g) << 10) + m) * 128 + ch;
        *(short8*)(oh + base) = h8;
        *(short8*)(ol + base) = l8;
    }
}

// ---------------------------------------------------------------------------
// scores_pv (round-20): 512 px-tiles x 1024 threads (16 waves). Per-wave
// work halved vs round-7/10: R and B one tile per wave; A+V split k-space
// across wave pairs (w, w+8), partials combined via two LDS tiles in F.
// No work duplication. XCD swizzle bz = lin&7.
// ---------------------------------------------------------------------------
__global__ __launch_bounds__(1024)
void scores_pv(const short* __restrict__ qhi, const short* __restrict__ qlo,
               const short* __restrict__ khi, const short* __restrict__ klo,
               const short* __restrict__ Wrh, const short* __restrict__ Wrl,
               const float* __restrict__ brel,
               const short* __restrict__ vhi, const short* __restrict__ vlo,
               const short* __restrict__ Vbh, const short* __restrict__ Vbl,
               short* __restrict__ AGhi, short* __restrict__ AGlo)
{
    __shared__ __align__(16) float qk[16 * 241];   // 15.4 KB; tile0 [16][133] in F
    __shared__ __align__(16) short pah[16 * 264];  // 8.25 KB; tile1 [16][132] in F
    __shared__ __align__(16) short pal[16 * 264];  // 8.25 KB
    __shared__ float invl[16];

    const int tid = threadIdx.x;
    const int wave = tid >> 6, lane = tid & 63;     // wave 0..15
    const int half = wave >> 3;                      // k-space half for A+V
    const int w8 = wave & 7;                         // ch-tile index
    const int lin = blockIdx.x;
    const int bz  = lin & 7;         // XCD-resident head/batch
    const int yy  = lin >> 3;        // 0..63
    const int y   = yy >> 1;
    const int xt  = yy & 1;
    const int g = bz & 1;
    const int x0 = xt * 16;

    const int n16 = lane & 15, quad = lane >> 4;
    const long qbase = (((long)bz << 10) + y * 32 + x0 + n16) * 128 + quad * 8;
    short8 a_hi[4], a_lo[4];
#pragma unroll
    for (int ch = 0; ch < 4; ++ch) {
        a_hi[ch] = *(const short8*)(qhi + qbase + ch * 32);
        a_lo[ch] = *(const short8*)(qlo + qbase + ch * 32);
    }

    // ---- phase R: rel logits (15 wt over 16 waves: one each) ----
    for (int wt = wave; wt < 15; wt += 16) {
        const short* Ah = Wrh + (long)g * 30720 + ((long)(wt * 4) * 64 + lane) * 8;
        const short* Al = Wrl + (long)g * 30720 + ((long)(wt * 4) * 64 + lane) * 8;
        floatx4 racc = {0.f, 0.f, 0.f, 0.f};
#pragma unroll
        for (int kc = 0; kc < 4; ++kc) {
            short8 whh = *(const short8*)(Ah + kc * 512);
            short8 wll = *(const short8*)(Al + kc * 512);
            racc = __builtin_amdgcn_mfma_f32_16x16x32_bf16(whh, a_hi[kc], racc, 0, 0, 0);
            racc = __builtin_amdgcn_mfma_f32_16x16x32_bf16(whh, a_lo[kc], racc, 0, 0, 0);
            racc = __builtin_amdgcn_mfma_f32_16x16x32_bf16(wll, a_hi[kc], racc, 0, 0, 0);
        }
#pragma unroll
        for (int r = 0; r < 4; ++r) {
            int w = wt * 16 + quad * 4 + r;
            if (w < 225) {
                int dy = w / 15, dx = w - dy * 15;
                qk[n16 * 241 + dy * 16 + dx] = racc[r] + brel[g * 225 + w];
            }
        }
    }
    __syncthreads();

    // ---- phase M: mask invalid neighbors and pad slots ----
    for (int e = tid; e < 16 * 241; e += 1024) {
        int px = e / 241, idx = e - px * 241;
        int dy = idx >> 4, dx = idx & 15;
        int hy = y + dy - 7, hx = x0 + px + dx - 7;
        bool valid = (dx < 15) && (dy < 15) &&
                     (hy >= 0) && (hy < 32) && (hx >= 0) && (hx < 32);
        if (!valid) qk[e] = -1e8f;
    }
    __syncthreads();

    // ---- phase B: band QK^T (15 dy over 16 waves: one each) ----
    for (int dy = wave; dy < 15; dy += 16) {
        const int ky = y + dy - 7;
        if (ky < 0 || ky > 31) continue;
#pragma unroll
        for (int kxt = 0; kxt < 2; ++kxt) {
            const int kxg = x0 - 8 + kxt * 16 + n16;
            const long kb = (((long)bz << 10) + ky * 32 + kxg) * 128 + quad * 8;
            floatx4 acc = {0.f, 0.f, 0.f, 0.f};
#pragma unroll
            for (int ch = 0; ch < 4; ++ch) {
                short8 b_hi = *(const short8*)(khi + kb + ch * 32);
                short8 b_lo = *(const short8*)(klo + kb + ch * 32);
                acc = __builtin_amdgcn_mfma_f32_16x16x32_bf16(a_hi[ch], b_hi, acc, 0, 0, 0);
                acc = __builtin_amdgcn_mfma_f32_16x16x32_bf16(a_hi[ch], b_lo, acc, 0, 0, 0);
                acc = __builtin_amdgcn_mfma_f32_16x16x32_bf16(a_lo[ch], b_hi, acc, 0, 0, 0);
            }
            if (kxg >= 0 && kxg < 32) {
#pragma unroll
                for (int r = 0; r < 4; ++r) {
                    int m = quad * 4 + r;
                    int dx = kxg - (x0 + m) + 7;
                    if (dx >= 0 && dx < 15) {
                        int s = m * 241 + dy * 16 + dx;
                        qk[s] = qk[s] + acc[r];
                    }
                }
            }
        }
    }
    __syncthreads();

    // ---- softmax: 64 lanes per px row ----
    {
        int px = tid >> 6, s = tid & 63;
        float mx = -3.0e38f;
        for (int w = s; w < 240; w += 64) mx = fmaxf(mx, qk[px * 241 + w]);
#pragma unroll
        for (int msk = 32; msk; msk >>= 1) mx = fmaxf(mx, __shfl_xor(mx, msk));
        float sum = 0.f;
        for (int w = s; w < 240; w += 64) {
            float p = __expf(qk[px * 241 + w] - mx);
            qk[px * 241 + w] = p;
            sum += p;
        }
#pragma unroll
        for (int msk = 32; msk; msk >>= 1) sum += __shfl_xor(sum, msk);
        if (s == 0) invl[px] = 1.0f / sum;
    }
    __syncthreads();

    // ---- phase T: normalize + bf16 hi/lo into pah/pal (w >= 225 -> 0) ----
    for (int e = tid; e < 4096; e += 1024) {
        int px = e >> 8, w = e & 255;
        float p = 0.f;
        if (w < 225) {
            int dy2 = w / 15, dx2 = w - dy2 * 15;
            p = qk[px * 241 + dy2 * 16 + dx2] * invl[px];
        }
        short hb = f2bf(p);
        pah[px * 264 + w] = hb;
        pal[px * 264 + w] = f2bf(p - bf2f(hb));
    }
    __syncthreads();

    // ---- phases A+V: 8 ch-tiles x 2 k-halves across 16 waves ----
    floatx4 acc = {0.f, 0.f, 0.f, 0.f};
    const int ch0 = w8 * 16;

    // (A) bias GEMM half: wk = half*4 .. +4
#pragma unroll
    for (int i = 0; i < 4; ++i) {
        const int wk = half * 4 + i;
        short8 pa_h = *(const short8*)&pah[n16 * 264 + wk * 32 + quad * 8];
        short8 pa_l = *(const short8*)&pal[n16 * 264 + wk * 32 + quad * 8];
        const long vb0 = (((long)(g * 128 + ch0 + n16)) << 8) + wk * 32 + quad * 8;
        short8 b0h = *(const short8*)(Vbh + vb0);
        short8 b0l = *(const short8*)(Vbl + vb0);
        acc = __builtin_amdgcn_mfma_f32_16x16x32_bf16(pa_h, b0h, acc, 0, 0, 0);
        acc = __builtin_amdgcn_mfma_f32_16x16x32_bf16(pa_h, b0l, acc, 0, 0, 0);
        acc = __builtin_amdgcn_mfma_f32_16x16x32_bf16(pa_l, b0h, acc, 0, 0, 0);
    }

    // (V) banded GEMM half: dy = half*8 .. min(+8, 15)
    for (int i = 0; i < 8; ++i) {
        const int dy = half * 8 + i;
        if (dy >= 15) break;
        const int ky = y + dy - 7;
        if (ky < 0 || ky > 31) continue;
        short8 bnd_h, bnd_l;
        const int rowoff = n16 * 264 + dy * 15 - n16 - 1;
#pragma unroll
        for (int j = 0; j < 8; ++j) {
            int kk = quad * 8 + j;
            int dx = kk - n16 - 1;
            bool valid = (unsigned)dx < 15u;
            int idx = valid ? (rowoff + kk) : 0;
            short vh = pah[idx];
            short vl = pal[idx];
            bnd_h[j] = valid ? vh : (short)0;
            bnd_l[j] = valid ? vl : (short)0;
        }
        const long v0o = (((long)((bz * 128 + ch0 + n16)) * 32 + ky)) * 48 + x0 + quad * 8;
        short8 v0h = *(const short8*)(vhi + v0o);
        short8 v0l = *(const short8*)(vlo + v0o);
        acc = __builtin_amdgcn_mfma_f32_16x16x32_bf16(bnd_h, v0h, acc, 0, 0, 0);
        acc = __builtin_amdgcn_mfma_f32_16x16x32_bf16(bnd_h, v0l, acc, 0, 0, 0);
        acc = __builtin_amdgcn_mfma_f32_16x16x32_bf16(bnd_l, v0h, acc, 0, 0, 0);
    }

    // ---- phase F: stage two partial tiles, sum, AG frag conversion ----
    // half 0 -> tile0 (qk, stride 133); half 1 -> tile1 (pah, stride 132).
    __syncthreads();                     // pah/pal band reads done (tile1 overwrites pah)
    float* tile0 = qk;
    float* tile1 = (float*)pah;
    {
        float* tl = half ? tile1 : tile0;
        const int strd = half ? 132 : 133;
        const int cb = ch0 + n16;
#pragma unroll
        for (int r = 0; r < 4; ++r)
            tl[(quad * 4 + r) * strd + cb] = acc[r];
    }
    __syncthreads();

    if (wave < 4) {
        short8 h8, l8;
#pragma unroll
        for (int j = 0; j < 8; ++j) {
            int col = wave * 32 + quad * 8 + j;
            float f = tile0[n16 * 133 + col] + tile1[n16 * 132 + col];
            short hb = f2bf(f);
            h8[j] = hb;
            l8[j] = f2bf(f - bf2f(hb));
        }
        const int n = bz >> 1;
        const int mt16 = y * 2 + xt;
        const int kc = g * 4 + wave;
        long off = (long)n * 262144 + (((long)(mt16 * 8 + kc) * 64) + lane) * 8;
        *(short8*)(AGhi + off) = h8;
        *(short8*)(AGlo + off) = l8;
    }
}

// ---------------------------------------------------------------------------
// mfma_fc v2 (round-10 verbatim): grid (mt16 64, db 4, nz 4) = 1024 blocks.
// ---------------------------------------------------------------------------
__global__ __launch_bounds__(256)
void mfma_fc(const short* __restrict__ Ahi, const short* __restrict__ Alo,
             const short* __restrict__ Whi, const short* __restrict__ Wlo,
             const float* __restrict__ bfc, float* __restrict__ out)
{
    __shared__ float tile[16 * 68];
    const int tid = threadIdx.x;
    const int wave = tid >> 6, lane = tid & 63;
    const int n16 = lane & 15, quad = lane >> 4;
    const int mt16 = blockIdx.x, db = blockIdx.y, nz = blockIdx.z;
    const int dt = db * 4 + wave;

    const short* Ah = Whi + (long)3 * 65536 + ((long)(dt * 8) * 64 + lane) * 8;
    const short* Al = Wlo + (long)3 * 65536 + ((long)(dt * 8) * 64 + lane) * 8;
    const short* Bh = Ahi + (long)nz * 262144;
    const short* Bl = Alo + (long)nz * 262144;

    float4 bv4 = *(const float4*)&bfc[dt * 16 + quad * 4];
    float bb[4] = {bv4.x, bv4.y, bv4.z, bv4.w};

    floatx4 acc = {0.f, 0.f, 0.f, 0.f};
#pragma unroll
    for (int kc = 0; kc < 8; ++kc) {
        short8 ahi = *(const short8*)(Ah + kc * 512);
        short8 alo = *(const short8*)(Al + kc * 512);
        long bo = ((long)(mt16 * 8 + kc) * 64 + lane) * 8;
        short8 bh = *(const short8*)(Bh + bo);
        short8 bl = *(const short8*)(Bl + bo);
        acc = __builtin_amdgcn_mfma_f32_16x16x32_bf16(ahi, bh, acc, 0, 0, 0);
        acc = __builtin_amdgcn_mfma_f32_16x16x32_bf16(ahi, bl, acc, 0, 0, 0);
        acc = __builtin_amdgcn_mfma_f32_16x16x32_bf16(alo, bh, acc, 0, 0, 0);
    }

    const int dl = wave * 16 + quad * 4;
#pragma unroll
    for (int r = 0; r < 4; ++r)
        tile[n16 * 68 + dl + r] = acc[r] + bb[r];
    __syncthreads();

    const int mm = tid >> 4, d4 = (tid & 15) * 4;
    float4 o4 = *(const float4*)&tile[mm * 68 + d4];
    *(float4*)&out[(long)(mt16 * 16 + mm) * 1024 + nz * 256 + db * 64 + d4] = o4;
}

// ---------------------------------------------------------------------------
// ws floats:
//   vhi@2097152 (786432 fl as shorts) vlo@2883584
//   Vbh@4718592 (32768 fl) Vbl@4751360
//   qhi@6561792 qlo@7086080 khi@7610368 klo@8134656 (524288 each)
//   Whi@11804672 (131072, 4 sels) Wlo@11935744
//   AGhi@12066816 (524288) AGlo@12591104
//   Wrh@13115392 (30720) Wrl@13146112
// ---------------------------------------------------------------------------
extern "C" void kernel_launch(void* const* d_in, const int* in_sizes, int n_in,
                              void* d_out, int out_size, void* d_ws, size_t ws_size,
                              hipStream_t stream)
{
    const float* q    = (const float*)d_in[0];
    const float* k    = (const float*)d_in[1];
    const float* v    = (const float*)d_in[2];
    const float* Wq   = (const float*)d_in[3];
    const float* bq   = (const float*)d_in[4];
    const float* Wk   = (const float*)d_in[5];
    const float* bk   = (const float*)d_in[6];
    const float* Wv   = (const float*)d_in[7];
    const float* bv   = (const float*)d_in[8];
    const float* Wrel = (const float*)d_in[9];
    const float* brel = (const float*)d_in[10];
    const float* Vb   = (const float*)d_in[11];
    const float* Wfc  = (const float*)d_in[12];
    const float* bfc  = (const float*)d_in[13];
    float* out = (float*)d_out;

    float* ws   = (float*)d_ws;
    short* vhi  = (short*)(ws + 2097152);
    short* vlo  = (short*)(ws + 2883584);
    short* Vbh  = (short*)(ws + 4718592);
    short* Vbl  = (short*)(ws + 4751360);
    short* qhi  = (short*)(ws + 6561792);
    short* qlo  = (short*)(ws + 7086080);
    short* khi  = (short*)(ws + 7610368);
    short* klo  = (short*)(ws + 8134656);
    short* Whi  = (short*)(ws + 11804672);
    short* Wlo  = (short*)(ws + 11935744);
    short* AGhi = (short*)(ws + 12066816);
    short* AGlo = (short*)(ws + 12591104);
    short* Wrh  = (short*)(ws + 13115392);
    short* Wrl  = (short*)(ws + 13146112);

    // fragment conversion: Wq/Wk/Wv/Wfc A-frags, Wrel, V_bias rows
    prep<<<dim3(190), dim3(256), 0, stream>>>(Wq, Wk, Wv, Wfc, Wrel, Vb,
                                              Whi, Wlo, Wrh, Wrl, Vbh, Vbl);

    // QKV projections (pre-converted A-frags): 768 blocks
    mfma_proj<<<dim3(64, 12), dim3(256), 0, stream>>>(q, k, v, Whi, Wlo,
                                                      bq, bk, bv,
                                                      qhi, qlo, khi, klo,
                                                      vhi, vlo);

    // rel + scores + softmax + MFMA PV -> AG frags: 512 x 1024 threads
    scores_pv<<<dim3(512), dim3(1024), 0, stream>>>(qhi, qlo, khi, klo,
                                                    Wrh, Wrl, brel,
                                                    vhi, vlo, Vbh, Vbl,
                                                    AGhi, AGlo);

    // FC via MFMA: 1024 blocks (4/CU)
    mfma_fc<<<dim3(64, 4, 4), dim3(256), 0, stream>>>(AGhi, AGlo, Whi, Wlo,
                                                      bfc, out);
}

// Round 14
// 154.967 us; speedup vs baseline: 1.1194x; 1.0248x over previous
//
#include <hip/hip_runtime.h>
#include <math.h>

// N=4, C=256, H=W=32, NH=2, HD=128, MAX_DIS=7, WS=15, WW=225, T=sqrt(128)
// out: [hw=1024][n=4][c=256] fp32
// Round-14 (= round-13 resubmit, restrict-aliasing fixed):
//  - scores: 8-wave (47.4us proven) with mask phase M folded into R
//    (one fewer barrier + LDS pass; identical values).
//  - prep: Wq/Wk/Wv only (gates proj). Wfc/Wrel/Vb conversion in proj z==12
//    slice (consumed only by scores/fc -> no race, off critical chain).

typedef __attribute__((ext_vector_type(8))) short short8;
typedef __attribute__((ext_vector_type(4))) float floatx4;

__device__ __forceinline__ short f2bf(float f) {
    unsigned u = __float_as_uint(f);
    unsigned r = (u + 0x7fffu + ((u >> 16) & 1u)) >> 16;
    return (short)r;
}
__device__ __forceinline__ float bf2f(short s) {
    return __uint_as_float(((unsigned)(unsigned short)s) << 16);
}

// ---------------------------------------------------------------------------
// prep v4: Wq/Wk/Wv A-frags only (384 wave-units, 4/block, grid 96 x 256).
// ---------------------------------------------------------------------------
__global__ __launch_bounds__(256)
void prep(const float* __restrict__ Wq, const float* __restrict__ Wk,
          const float* __restrict__ Wv,
          short* __restrict__ Whi, short* __restrict__ Wlo)
{
    const int tid = threadIdx.x;
    const int sub = tid >> 6, lane = tid & 63;
    const int n16 = lane & 15, quad = lane >> 4;
    const int u = blockIdx.x * 4 + sub;          // 0..383

    const int sel = u >> 7, rem = u & 127;
    const int dt = rem >> 3, kc = rem & 7;
    const float* W = (sel == 0 ? Wq : sel == 1 ? Wk : Wv);
    const int d = dt * 16 + n16, cb = kc * 32 + quad * 8;
    float4 w0 = *(const float4*)&W[(long)d * 256 + cb];
    float4 w1 = *(const float4*)&W[(long)d * 256 + cb + 4];
    float f[8] = {w0.x, w0.y, w0.z, w0.w, w1.x, w1.y, w1.z, w1.w};
    short8 h8, l8;
#pragma unroll
    for (int j = 0; j < 8; ++j) {
        short hb = f2bf(f[j]);
        h8[j] = hb;
        l8[j] = f2bf(f[j] - bf2f(hb));
    }
    long off = (long)sel * 65536 + (((long)(dt * 8 + kc) * 64) + lane) * 8;
    *(short8*)(Whi + off) = h8;
    *(short8*)(Wlo + off) = l8;
}

// ---------------------------------------------------------------------------
// mfma_proj v9: round-10 proj + z==12 constants slice (Wfc/Wrel/Vb frags).
// Whi/Wlo passed ONCE (no restrict): z<12 reads sel 0..2 region, z==12
// writes sel-3 region — disjoint, no race.
// grid (64, 13); z<12: sel = z>>2 (0=q,1=k,2=v), batch = z&3.
// ---------------------------------------------------------------------------
__global__ __launch_bounds__(256)
void mfma_proj(const float* __restrict__ q, const float* __restrict__ k,
               const float* __restrict__ v,
               const float* __restrict__ Wfc, const float* __restrict__ Wrel,
               const float* __restrict__ Vb,
               short* Whi, short* Wlo,
               const float* __restrict__ bq, const float* __restrict__ bk,
               const float* __restrict__ bv,
               short* __restrict__ qhi, short* __restrict__ qlo,
               short* __restrict__ khi, short* __restrict__ klo,
               short* __restrict__ vhi, short* __restrict__ vlo,
               short* __restrict__ Wrh, short* __restrict__ Wrl,
               short* __restrict__ Vbh, short* __restrict__ Vbl)
{
    __shared__ float st[256 * 17];
    const int tid = threadIdx.x;
    const int wave = tid >> 6, lane = tid & 63;
    const int n16 = lane & 15, quad = lane >> 4;
    const int z = blockIdx.y;

    if (z == 12) {
        // constants conversion: 512 wave-unit capacity, 376 used
#pragma unroll
        for (int s = 0; s < 2; ++s) {
            const int u = blockIdx.x * 8 + wave * 2 + s;
            if (u < 128) {
                const int dt = u >> 3, kc = u & 7;
                const int d = dt * 16 + n16, cb = kc * 32 + quad * 8;
                float4 w0 = *(const float4*)&Wfc[(long)d * 256 + cb];
                float4 w1 = *(const float4*)&Wfc[(long)d * 256 + cb + 4];
                float f[8] = {w0.x, w0.y, w0.z, w0.w, w1.x, w1.y, w1.z, w1.w};
                short8 h8, l8;
#pragma unroll
                for (int j = 0; j < 8; ++j) {
                    short hb = f2bf(f[j]);
                    h8[j] = hb;
                    l8[j] = f2bf(f[j] - bf2f(hb));
                }
                long off = (long)3 * 65536 + (((long)(dt * 8 + kc) * 64) + lane) * 8;
                *(short8*)(Whi + off) = h8;
                *(short8*)(Wlo + off) = l8;
            } else if (u < 248) {
                const int t = u - 128;
                const int g = t / 60, r = t - g * 60;
                const int wt = r >> 2, kc = r & 3;
                const int w = wt * 16 + n16;
                const int cb = kc * 32 + quad * 8;
                float f[8] = {0.f, 0.f, 0.f, 0.f, 0.f, 0.f, 0.f, 0.f};
                if (w < 225) {
                    float4 w0 = *(const float4*)&Wrel[(long)(g * 225 + w) * 128 + cb];
                    float4 w1 = *(const float4*)&Wrel[(long)(g * 225 + w) * 128 + cb + 4];
                    f[0] = w0.x; f[1] = w0.y; f[2] = w0.z; f[3] = w0.w;
                    f[4] = w1.x; f[5] = w1.y; f[6] = w1.z; f[7] = w1.w;
                }
                short8 h8, l8;
#pragma unroll
                for (int j = 0; j < 8; ++j) {
                    short hb = f2bf(f[j]);
                    h8[j] = hb;
                    l8[j] = f2bf(f[j] - bf2f(hb));
                }
                long off = (long)g * 30720 + (((long)(wt * 4 + kc) * 64) + lane) * 8;
                *(short8*)(Wrh + off) = h8;
                *(short8*)(Wrl + off) = l8;
            } else if (u < 376) {
                const int t = u - 248;
                const int g = t >> 6, r = t & 63;
                const int dt = r >> 3, wk = r & 7;
                const int ch = dt * 16 + n16;
                const int w0 = wk * 32 + quad * 8;
                float f[8];
#pragma unroll
                for (int j = 0; j < 8; ++j) {
                    int w = w0 + j;
                    f[j] = (w < 225) ? Vb[(long)(g * 128 + ch) * 225 + w] : 0.f;
                }
                short8 h8, l8;
#pragma unroll
                for (int j = 0; j < 8; ++j) {
                    short hb = f2bf(f[j]);
                    h8[j] = hb;
                    l8[j] = f2bf(f[j] - bf2f(hb));
                }
                long off = (((long)(g * 128 + ch)) << 8) + w0;
                *(short8*)(Vbh + off) = h8;
                *(short8*)(Vbl + off) = l8;
            }
        }
        return;
    }

    const int mt16 = blockIdx.x;
    const int sel = z >> 2, batch = z & 3;
    const float* X = (sel == 0 ? q : sel == 1 ? k : v) + ((long)batch << 18);

    {
        const float* src = X + ((long)tid << 10) + mt16 * 16;
        float4 a0 = *(const float4*)(src);
        float4 a1 = *(const float4*)(src + 4);
        float4 a2 = *(const float4*)(src + 8);
        float4 a3 = *(const float4*)(src + 12);
        float* d = &st[tid * 17];
        d[0] = a0.x; d[1] = a0.y; d[2] = a0.z; d[3] = a0.w;
        d[4] = a1.x; d[5] = a1.y; d[6] = a1.z; d[7] = a1.w;
        d[8] = a2.x; d[9] = a2.y; d[10] = a2.z; d[11] = a2.w;
        d[12] = a3.x; d[13] = a3.y; d[14] = a3.z; d[15] = a3.w;
    }

    const float* bias = (sel == 0 ? bq : sel == 1 ? bk : bv);
    float bbv[4][4];
#pragma unroll
    for (int i = 0; i < 4; ++i) {
        float4 b4 = *(const float4*)&bias[(wave * 4 + i) * 16 + quad * 4];
        bbv[i][0] = b4.x; bbv[i][1] = b4.y; bbv[i][2] = b4.z; bbv[i][3] = b4.w;
    }
    __syncthreads();

    floatx4 acc[4] = {{0.f,0.f,0.f,0.f},{0.f,0.f,0.f,0.f},
                      {0.f,0.f,0.f,0.f},{0.f,0.f,0.f,0.f}};
    const long abase = (long)sel * 65536 + (long)lane * 8;
#pragma unroll
    for (int kc = 0; kc < 8; ++kc) {
        short8 bh, bl;
        const float* col = &st[(kc * 32 + quad * 8) * 17 + n16];
#pragma unroll
        for (int j = 0; j < 8; ++j) {
            float f = col[j * 17];
            short hb = f2bf(f);
            bh[j] = hb;
            bl[j] = f2bf(f - bf2f(hb));
        }
#pragma unroll
        for (int i = 0; i < 4; ++i) {
            const int dt = wave * 4 + i;
            short8 ahi = *(const short8*)(Whi + abase + (long)(dt * 8 + kc) * 512);
            short8 alo = *(const short8*)(Wlo + abase + (long)(dt * 8 + kc) * 512);
            acc[i] = __builtin_amdgcn_mfma_f32_16x16x32_bf16(ahi, bh, acc[i], 0, 0, 0);
            acc[i] = __builtin_amdgcn_mfma_f32_16x16x32_bf16(ahi, bl, acc[i], 0, 0, 0);
            acc[i] = __builtin_amdgcn_mfma_f32_16x16x32_bf16(alo, bh, acc[i], 0, 0, 0);
        }
    }

    __syncthreads();
    float* tile = st;
#pragma unroll
    for (int i = 0; i < 4; ++i) {
        const int dt = wave * 4 + i;
#pragma unroll
        for (int r = 0; r < 4; ++r)
            tile[n16 * 257 + dt * 16 + quad * 4 + r] = acc[i][r] + bbv[i][r];
    }
    __syncthreads();

    if (sel == 2) {
        const int gg = tid >> 7, chp = tid & 127;
        const int yq = mt16 >> 1, xb = (mt16 & 1) * 16;
        short8 h0, h1, l0, l1;
#pragma unroll
        for (int j = 0; j < 8; ++j) {
            float f0 = tile[j * 257 + tid];
            float f1 = tile[(j + 8) * 257 + tid];
            short hb0 = f2bf(f0), hb1 = f2bf(f1);
            h0[j] = hb0; l0[j] = f2bf(f0 - bf2f(hb0));
            h1[j] = hb1; l1[j] = f2bf(f1 - bf2f(hb1));
        }
        long o = ((long)((batch * 2 + gg) * 128 + chp) * 32 + yq) * 48 + 8 + xb;
        *(short8*)(vhi + o) = h0;
        *(short8*)(vhi + o + 8) = h1;
        *(short8*)(vlo + o) = l0;
        *(short8*)(vlo + o + 8) = l1;
        const int prow = mt16 >> 1, side = mt16 & 1;
        long po = ((long)((batch * 2 + gg) * 128 + chp) * 32 + prow) * 48 + side * 40;
        short8 zz = {0,0,0,0,0,0,0,0};
        *(short8*)(vhi + po) = zz;
        *(short8*)(vlo + po) = zz;
        return;
    }

    const float scale = (sel == 1) ? 0.08838834764831845f : 1.0f;
    const int m_l = tid >> 4, c16 = (tid & 15) * 16;
    const int m = mt16 * 16 + m_l;
    short* oh = sel ? khi : qhi;
    short* ol = sel ? klo : qlo;
#pragma unroll
    for (int half = 0; half < 2; ++half) {
        const int cg = c16 + half * 8;
        short8 h8, l8;
#pragma unroll
        for (int j = 0; j < 8; ++j) {
            float f = tile[m_l * 257 + cg + j] * scale;
            short hb = f2bf(f);
            h8[j] = hb;
            l8[j] = f2bf(f - bf2f(hb));
        }
        const int g = cg >> 7, ch = cg & 127;
        const long base = (((long)(batch * 2 + g) << 10) + m) * 128 + ch;
        *(short8*)(oh + base) = h8;
        *(short8*)(ol + base) = l8;
    }
}

// ---------------------------------------------------------------------------
// scores_pv (round-21): round-10 8-wave version with phase M folded into R.
// 512 px-tiles x 512 threads, XCD swizzle bz = lin&7.
// R writes valid slots (masked inline) + pad-slot init; barrier count 7 -> 6.
// ---------------------------------------------------------------------------
__global__ __launch_bounds__(512)
void scores_pv(const short* __restrict__ qhi, const short* __restrict__ qlo,
               const short* __restrict__ khi, const short* __restrict__ klo,
               const short* __restrict__ Wrh, const short* __restrict__ Wrl,
               const float* __restrict__ brel,
               const short* __restrict__ vhi, const short* __restrict__ vlo,
               const short* __restrict__ Vbh, const short* __restrict__ Vbl,
               short* __restrict__ AGhi, short* __restrict__ AGlo)
{
    __shared__ __align__(16) float qk[16 * 241];   // 15.4 KB; aliased as tile[16][133] in F
    __shared__ __align__(16) short pah[16 * 264];  // 8.25 KB
    __shared__ __align__(16) short pal[16 * 264];  // 8.25 KB
    __shared__ float invl[16];

    const int tid = threadIdx.x;
    const int wave = tid >> 6, lane = tid & 63;     // wave 0..7
    const int lin = blockIdx.x;
    const int bz  = lin & 7;
    const int yy  = lin >> 3;
    const int y   = yy >> 1;
    const int xt  = yy & 1;
    const int g = bz & 1;
    const int x0 = xt * 16;

    const int n16 = lane & 15, quad = lane >> 4;
    const long qbase = (((long)bz << 10) + y * 32 + x0 + n16) * 128 + quad * 8;
    short8 a_hi[4], a_lo[4];
#pragma unroll
    for (int ch = 0; ch < 4; ++ch) {
        a_hi[ch] = *(const short8*)(qhi + qbase + ch * 32);
        a_lo[ch] = *(const short8*)(qlo + qbase + ch * 32);
    }

    // ---- phase R: rel logits with inline boundary mask (M folded in) ----
    for (int wt = wave; wt < 15; wt += 8) {
        const short* Ah = Wrh + (long)g * 30720 + ((long)(wt * 4) * 64 + lane) * 8;
        const short* Al = Wrl + (long)g * 30720 + ((long)(wt * 4) * 64 + lane) * 8;
        floatx4 racc = {0.f, 0.f, 0.f, 0.f};
#pragma unroll
        for (int kc = 0; kc < 4; ++kc) {
            short8 whh = *(const short8*)(Ah + kc * 512);
            short8 wll = *(const short8*)(Al + kc * 512);
            racc = __builtin_amdgcn_mfma_f32_16x16x32_bf16(whh, a_hi[kc], racc, 0, 0, 0);
            racc = __builtin_amdgcn_mfma_f32_16x16x32_bf16(whh, a_lo[kc], racc, 0, 0, 0);
            racc = __builtin_amdgcn_mfma_f32_16x16x32_bf16(wll, a_hi[kc], racc, 0, 0, 0);
        }
#pragma unroll
        for (int r = 0; r < 4; ++r) {
            int w = wt * 16 + quad * 4 + r;
            if (w < 225) {
                int dy = w / 15, dx = w - dy * 15;
                int hy = y + dy - 7, hx = x0 + n16 + dx - 7;
                bool valid = (hy >= 0) && (hy < 32) && (hx >= 0) && (hx < 32);
                qk[n16 * 241 + dy * 16 + dx] =
                    valid ? (racc[r] + brel[g * 225 + w]) : -1e8f;
            }
        }
    }
    // pad slots (16 per px row: dy*16+15 and 240) -> -1e8
    if (tid < 256) {
        int px = tid >> 4, p = tid & 15;
        int slot = (p < 15) ? (p * 16 + 15) : 240;
        qk[px * 241 + slot] = -1e8f;
    }
    __syncthreads();

    // ---- phase B: band QK^T (15 dy over 8 waves) ----
    for (int dy = wave; dy < 15; dy += 8) {
        const int ky = y + dy - 7;
        if (ky < 0 || ky > 31) continue;
#pragma unroll
        for (int kxt = 0; kxt < 2; ++kxt) {
            const int kxg = x0 - 8 + kxt * 16 + n16;
            const long kb = (((long)bz << 10) + ky * 32 + kxg) * 128 + quad * 8;
            floatx4 acc = {0.f, 0.f, 0.f, 0.f};
#pragma unroll
            for (int ch = 0; ch < 4; ++ch) {
                short8 b_hi = *(const short8*)(khi + kb + ch * 32);
                short8 b_lo = *(const short8*)(klo + kb + ch * 32);
                acc = __builtin_amdgcn_mfma_f32_16x16x32_bf16(a_hi[ch], b_hi, acc, 0, 0, 0);
                acc = __builtin_amdgcn_mfma_f32_16x16x32_bf16(a_hi[ch], b_lo, acc, 0, 0, 0);
                acc = __builtin_amdgcn_mfma_f32_16x16x32_bf16(a_lo[ch], b_hi, acc, 0, 0, 0);
            }
            if (kxg >= 0 && kxg < 32) {
#pragma unroll
                for (int r = 0; r < 4; ++r) {
                    int m = quad * 4 + r;
                    int dx = kxg - (x0 + m) + 7;
                    if (dx >= 0 && dx < 15) {
                        int s = m * 241 + dy * 16 + dx;
                        qk[s] = qk[s] + acc[r];
                    }
                }
            }
        }
    }
    __syncthreads();

    // ---- softmax: 32 lanes per px row ----
    {
        int px = tid >> 5, s = tid & 31;
        float mx = -3.0e38f;
        for (int w = s; w < 240; w += 32) mx = fmaxf(mx, qk[px * 241 + w]);
#pragma unroll
        for (int msk = 16; msk; msk >>= 1) mx = fmaxf(mx, __shfl_xor(mx, msk));
        float sum = 0.f;
        for (int w = s; w < 240; w += 32) {
            float p = __expf(qk[px * 241 + w] - mx);
            qk[px * 241 + w] = p;
            sum += p;
        }
#pragma unroll
        for (int msk = 16; msk; msk >>= 1) sum += __shfl_xor(sum, msk);
        if (s == 0) invl[px] = 1.0f / sum;
    }
    __syncthreads();

    // ---- phase T: normalize + bf16 hi/lo into pah/pal (w >= 225 -> 0) ----
    for (int e = tid; e < 4096; e += 512) {
        int px = e >> 8, w = e & 255;
        float p = 0.f;
        if (w < 225) {
            int dy2 = w / 15, dx2 = w - dy2 * 15;
            p = qk[px * 241 + dy2 * 16 + dx2] * invl[px];
        }
        short hb = f2bf(p);
        pah[px * 264 + w] = hb;
        pal[px * 264 + w] = f2bf(p - bf2f(hb));
    }
    __syncthreads();

    // ---- phases A+V: MFMA accumulation, 1 ch-tile per wave (8 tiles) ----
    floatx4 acc = {0.f, 0.f, 0.f, 0.f};
    const int ch0 = wave * 16;

#pragma unroll
    for (int wk = 0; wk < 8; ++wk) {
        short8 pa_h = *(const short8*)&pah[n16 * 264 + wk * 32 + quad * 8];
        short8 pa_l = *(const short8*)&pal[n16 * 264 + wk * 32 + quad * 8];
        const long vb0 = (((long)(g * 128 + ch0 + n16)) << 8) + wk * 32 + quad * 8;
        short8 b0h = *(const short8*)(Vbh + vb0);
        short8 b0l = *(const short8*)(Vbl + vb0);
        acc = __builtin_amdgcn_mfma_f32_16x16x32_bf16(pa_h, b0h, acc, 0, 0, 0);
        acc = __builtin_amdgcn_mfma_f32_16x16x32_bf16(pa_h, b0l, acc, 0, 0, 0);
        acc = __builtin_amdgcn_mfma_f32_16x16x32_bf16(pa_l, b0h, acc, 0, 0, 0);
    }

    for (int dy = 0; dy < 15; ++dy) {
        const int ky = y + dy - 7;
        if (ky < 0 || ky > 31) continue;
        short8 bnd_h, bnd_l;
        const int rowoff = n16 * 264 + dy * 15 - n16 - 1;
#pragma unroll
        for (int j = 0; j < 8; ++j) {
            int kk = quad * 8 + j;
            int dx = kk - n16 - 1;
            bool valid = (unsigned)dx < 15u;
            int idx = valid ? (rowoff + kk) : 0;
            short vh = pah[idx];
            short vl = pal[idx];
            bnd_h[j] = valid ? vh : (short)0;
            bnd_l[j] = valid ? vl : (short)0;
        }
        const long v0o = (((long)((bz * 128 + ch0 + n16)) * 32 + ky)) * 48 + x0 + quad * 8;
        short8 v0h = *(const short8*)(vhi + v0o);
        short8 v0l = *(const short8*)(vlo + v0o);
        acc = __builtin_amdgcn_mfma_f32_16x16x32_bf16(bnd_h, v0h, acc, 0, 0, 0);
        acc = __builtin_amdgcn_mfma_f32_16x16x32_bf16(bnd_h, v0l, acc, 0, 0, 0);
        acc = __builtin_amdgcn_mfma_f32_16x16x32_bf16(bnd_l, v0h, acc, 0, 0, 0);
    }

    // ---- phase F: stage tile [16 px][128 ch] then AG frag conversion ----
    float* tile = qk;                    // [16][133]
    {
        const int cb = ch0 + n16;
#pragma unroll
        for (int r = 0; r < 4; ++r)
            tile[(quad * 4 + r) * 133 + cb] = acc[r];
    }
    __syncthreads();

    const int sub = tid >> 6;
    if (sub < 4) {
        short8 h8, l8;
#pragma unroll
        for (int j = 0; j < 8; ++j) {
            float f = tile[n16 * 133 + sub * 32 + quad * 8 + j];
            short hb = f2bf(f);
            h8[j] = hb;
            l8[j] = f2bf(f - bf2f(hb));
        }
        const int n = bz >> 1;
        const int mt16 = y * 2 + xt;
        const int kc = g * 4 + sub;
        long off = (long)n * 262144 + (((long)(mt16 * 8 + kc) * 64) + lane) * 8;
        *(short8*)(AGhi + off) = h8;
        *(short8*)(AGlo + off) = l8;
    }
}

// ---------------------------------------------------------------------------
// mfma_fc v2 (round-10 verbatim): grid (mt16 64, db 4, nz 4) = 1024 blocks.
// ---------------------------------------------------------------------------
__global__ __launch_bounds__(256)
void mfma_fc(const short* __restrict__ Ahi, const short* __restrict__ Alo,
             const short* __restrict__ Whi, const short* __restrict__ Wlo,
             const float* __restrict__ bfc, float* __restrict__ out)
{
    __shared__ float tile[16 * 68];
    const int tid = threadIdx.x;
    const int wave = tid >> 6, lane = tid & 63;
    const int n16 = lane & 15, quad = lane >> 4;
    const int mt16 = blockIdx.x, db = blockIdx.y, nz = blockIdx.z;
    const int dt = db * 4 + wave;

    const short* Ah = Whi + (long)3 * 65536 + ((long)(dt * 8) * 64 + lane) * 8;
    const short* Al = Wlo + (long)3 * 65536 + ((long)(dt * 8) * 64 + lane) * 8;
    const short* Bh = Ahi + (long)nz * 262144;
    const short* Bl = Alo + (long)nz * 262144;

    float4 bv4 = *(const float4*)&bfc[dt * 16 + quad * 4];
    float bb[4] = {bv4.x, bv4.y, bv4.z, bv4.w};

    floatx4 acc = {0.f, 0.f, 0.f, 0.f};
#pragma unroll
    for (int kc = 0; kc < 8; ++kc) {
        short8 ahi = *(const short8*)(Ah + kc * 512);
        short8 alo = *(const short8*)(Al + kc * 512);
        long bo = ((long)(mt16 * 8 + kc) * 64 + lane) * 8;
        short8 bh = *(const short8*)(Bh + bo);
        short8 bl = *(const short8*)(Bl + bo);
        acc = __builtin_amdgcn_mfma_f32_16x16x32_bf16(ahi, bh, acc, 0, 0, 0);
        acc = __builtin_amdgcn_mfma_f32_16x16x32_bf16(ahi, bl, acc, 0, 0, 0);
        acc = __builtin_amdgcn_mfma_f32_16x16x32_bf16(alo, bh, acc, 0, 0, 0);
    }

    const int dl = wave * 16 + quad * 4;
#pragma unroll
    for (int r = 0; r < 4; ++r)
        tile[n16 * 68 + dl + r] = acc[r] + bb[r];
    __syncthreads();

    const int mm = tid >> 4, d4 = (tid & 15) * 4;
    float4 o4 = *(const float4*)&tile[mm * 68 + d4];
    *(float4*)&out[(long)(mt16 * 16 + mm) * 1024 + nz * 256 + db * 64 + d4] = o4;
}

// ---------------------------------------------------------------------------
// ws floats:
//   vhi@2097152 (786432 fl as shorts) vlo@2883584
//   Vbh@4718592 (32768 fl) Vbl@4751360
//   qhi@6561792 qlo@7086080 khi@7610368 klo@8134656 (524288 each)
//   Whi@11804672 (131072, 4 sels) Wlo@11935744
//   AGhi@12066816 (524288) AGlo@12591104
//   Wrh@13115392 (30720) Wrl@13146112
// ---------------------------------------------------------------------------
extern "C" void kernel_launch(void* const* d_in, const int* in_sizes, int n_in,
                              void* d_out, int out_size, void* d_ws, size_t ws_size,
                              hipStream_t stream)
{
    const float* q    = (const float*)d_in[0];
    const float* k    = (const float*)d_in[1];
    const float* v    = (const float*)d_in[2];
    const float* Wq   = (const float*)d_in[3];
    const float* bq   = (const float*)d_in[4];
    const float* Wk   = (const float*)d_in[5];
    const float* bk   = (const float*)d_in[6];
    const float* Wv   = (const float*)d_in[7];
    const float* bv   = (const float*)d_in[8];
    const float* Wrel = (const float*)d_in[9];
    const float* brel = (const float*)d_in[10];
    const float* Vb   = (const float*)d_in[11];
    const float* Wfc  = (const float*)d_in[12];
    const float* bfc  = (const float*)d_in[13];
    float* out = (float*)d_out;

    float* ws   = (float*)d_ws;
    short* vhi  = (short*)(ws + 2097152);
    short* vlo  = (short*)(ws + 2883584);
    short* Vbh  = (short*)(ws + 4718592);
    short* Vbl  = (short*)(ws + 4751360);
    short* qhi  = (short*)(ws + 6561792);
    short* qlo  = (short*)(ws + 7086080);
    short* khi  = (short*)(ws + 7610368);
    short* klo  = (short*)(ws + 8134656);
    short* Whi  = (short*)(ws + 11804672);
    short* Wlo  = (short*)(ws + 11935744);
    short* AGhi = (short*)(ws + 12066816);
    short* AGlo = (short*)(ws + 12591104);
    short* Wrh  = (short*)(ws + 13115392);
    short* Wrl  = (short*)(ws + 13146112);

    // Wq/Wk/Wv A-frags only (gates proj): 96 blocks
    prep<<<dim3(96), dim3(256), 0, stream>>>(Wq, Wk, Wv, Whi, Wlo);

    // QKV projections + constants conversion (z==12): 832 blocks
    mfma_proj<<<dim3(64, 13), dim3(256), 0, stream>>>(q, k, v, Wfc, Wrel, Vb,
                                                      Whi, Wlo,
                                                      bq, bk, bv,
                                                      qhi, qlo, khi, klo,
                                                      vhi, vlo,
                                                      Wrh, Wrl, Vbh, Vbl);

    // rel(+mask) + band QK^T + softmax + MFMA PV -> AG frags: 512 x 512
    scores_pv<<<dim3(512), dim3(512), 0, stream>>>(qhi, qlo, khi, klo,
                                                   Wrh, Wrl, brel,
                                                   vhi, vlo, Vbh, Vbl,
                                                   AGhi, AGlo);

    // FC via MFMA: 1024 blocks (4/CU)
    mfma_fc<<<dim3(64, 4, 4), dim3(256), 0, stream>>>(AGhi, AGlo, Whi, Wlo,
                                                      bfc, out);
}

// Round 15
// 153.845 us; speedup vs baseline: 1.1275x; 1.0073x over previous
//
#include <hip/hip_runtime.h>
#include <math.h>

// N=4, C=256, H=W=32, NH=2, HD=128, MAX_DIS=7, WS=15, WW=225, T=sqrt(128)
// out: [hw=1024][n=4][c=256] fp32
// Round-15 (from round-14 best, 155.0us): single change — mfma_proj staging
// load coalesced (was 64 lanes x 16B at 4KB stride = 4x line over-fetch of
// the 12MB raw input; now lane-quads read contiguous 64B). Values staged to
// identical st[] slots -> bit-identical outputs.

typedef __attribute__((ext_vector_type(8))) short short8;
typedef __attribute__((ext_vector_type(4))) float floatx4;

__device__ __forceinline__ short f2bf(float f) {
    unsigned u = __float_as_uint(f);
    unsigned r = (u + 0x7fffu + ((u >> 16) & 1u)) >> 16;
    return (short)r;
}
__device__ __forceinline__ float bf2f(short s) {
    return __uint_as_float(((unsigned)(unsigned short)s) << 16);
}

// ---------------------------------------------------------------------------
// prep v4: Wq/Wk/Wv A-frags only (384 wave-units, 4/block, grid 96 x 256).
// ---------------------------------------------------------------------------
__global__ __launch_bounds__(256)
void prep(const float* __restrict__ Wq, const float* __restrict__ Wk,
          const float* __restrict__ Wv,
          short* __restrict__ Whi, short* __restrict__ Wlo)
{
    const int tid = threadIdx.x;
    const int sub = tid >> 6, lane = tid & 63;
    const int n16 = lane & 15, quad = lane >> 4;
    const int u = blockIdx.x * 4 + sub;          // 0..383

    const int sel = u >> 7, rem = u & 127;
    const int dt = rem >> 3, kc = rem & 7;
    const float* W = (sel == 0 ? Wq : sel == 1 ? Wk : Wv);
    const int d = dt * 16 + n16, cb = kc * 32 + quad * 8;
    float4 w0 = *(const float4*)&W[(long)d * 256 + cb];
    float4 w1 = *(const float4*)&W[(long)d * 256 + cb + 4];
    float f[8] = {w0.x, w0.y, w0.z, w0.w, w1.x, w1.y, w1.z, w1.w};
    short8 h8, l8;
#pragma unroll
    for (int j = 0; j < 8; ++j) {
        short hb = f2bf(f[j]);
        h8[j] = hb;
        l8[j] = f2bf(f[j] - bf2f(hb));
    }
    long off = (long)sel * 65536 + (((long)(dt * 8 + kc) * 64) + lane) * 8;
    *(short8*)(Whi + off) = h8;
    *(short8*)(Wlo + off) = l8;
}

// ---------------------------------------------------------------------------
// mfma_proj v10: coalesced staging. grid (64, 13); z<12: sel = z>>2
// (0=q,1=k,2=v), batch = z&3; z==12: constants conversion slice.
// Whi/Wlo passed once (no restrict): z<12 reads sel 0..2, z==12 writes sel 3.
// ---------------------------------------------------------------------------
__global__ __launch_bounds__(256)
void mfma_proj(const float* __restrict__ q, const float* __restrict__ k,
               const float* __restrict__ v,
               const float* __restrict__ Wfc, const float* __restrict__ Wrel,
               const float* __restrict__ Vb,
               short* Whi, short* Wlo,
               const float* __restrict__ bq, const float* __restrict__ bk,
               const float* __restrict__ bv,
               short* __restrict__ qhi, short* __restrict__ qlo,
               short* __restrict__ khi, short* __restrict__ klo,
               short* __restrict__ vhi, short* __restrict__ vlo,
               short* __restrict__ Wrh, short* __restrict__ Wrl,
               short* __restrict__ Vbh, short* __restrict__ Vbl)
{
    __shared__ float st[256 * 17];
    const int tid = threadIdx.x;
    const int wave = tid >> 6, lane = tid & 63;
    const int n16 = lane & 15, quad = lane >> 4;
    const int z = blockIdx.y;

    if (z == 12) {
        // constants conversion: 512 wave-unit capacity, 376 used
#pragma unroll
        for (int s = 0; s < 2; ++s) {
            const int u = blockIdx.x * 8 + wave * 2 + s;
            if (u < 128) {
                const int dt = u >> 3, kc = u & 7;
                const int d = dt * 16 + n16, cb = kc * 32 + quad * 8;
                float4 w0 = *(const float4*)&Wfc[(long)d * 256 + cb];
                float4 w1 = *(const float4*)&Wfc[(long)d * 256 + cb + 4];
                float f[8] = {w0.x, w0.y, w0.z, w0.w, w1.x, w1.y, w1.z, w1.w};
                short8 h8, l8;
#pragma unroll
                for (int j = 0; j < 8; ++j) {
                    short hb = f2bf(f[j]);
                    h8[j] = hb;
                    l8[j] = f2bf(f[j] - bf2f(hb));
                }
                long off = (long)3 * 65536 + (((long)(dt * 8 + kc) * 64) + lane) * 8;
                *(short8*)(Whi + off) = h8;
                *(short8*)(Wlo + off) = l8;
            } else if (u < 248) {
                const int t = u - 128;
                const int g = t / 60, r = t - g * 60;
                const int wt = r >> 2, kc = r & 3;
                const int w = wt * 16 + n16;
                const int cb = kc * 32 + quad * 8;
                float f[8] = {0.f, 0.f, 0.f, 0.f, 0.f, 0.f, 0.f, 0.f};
                if (w < 225) {
                    float4 w0 = *(const float4*)&Wrel[(long)(g * 225 + w) * 128 + cb];
                    float4 w1 = *(const float4*)&Wrel[(long)(g * 225 + w) * 128 + cb + 4];
                    f[0] = w0.x; f[1] = w0.y; f[2] = w0.z; f[3] = w0.w;
                    f[4] = w1.x; f[5] = w1.y; f[6] = w1.z; f[7] = w1.w;
                }
                short8 h8, l8;
#pragma unroll
                for (int j = 0; j < 8; ++j) {
                    short hb = f2bf(f[j]);
                    h8[j] = hb;
                    l8[j] = f2bf(f[j] - bf2f(hb));
                }
                long off = (long)g * 30720 + (((long)(wt * 4 + kc) * 64) + lane) * 8;
                *(short8*)(Wrh + off) = h8;
                *(short8*)(Wrl + off) = l8;
            } else if (u < 376) {
                const int t = u - 248;
                const int g = t >> 6, r = t & 63;
                const int dt = r >> 3, wk = r & 7;
                const int ch = dt * 16 + n16;
                const int w0 = wk * 32 + quad * 8;
                float f[8];
#pragma unroll
                for (int j = 0; j < 8; ++j) {
                    int w = w0 + j;
                    f[j] = (w < 225) ? Vb[(long)(g * 128 + ch) * 225 + w] : 0.f;
                }
                short8 h8, l8;
#pragma unroll
                for (int j = 0; j < 8; ++j) {
                    short hb = f2bf(f[j]);
                    h8[j] = hb;
                    l8[j] = f2bf(f[j] - bf2f(hb));
                }
                long off = (((long)(g * 128 + ch)) << 8) + w0;
                *(short8*)(Vbh + off) = h8;
                *(short8*)(Vbl + off) = l8;
            }
        }
        return;
    }

    const int mt16 = blockIdx.x;
    const int sel = z >> 2, batch = z & 3;
    const float* X = (sel == 0 ? q : sel == 1 ? k : v) + ((long)batch << 18);

    // ---- stage X tile, COALESCED: pass p, thread t -> c = p*64 + (t>>2),
    // m4 = (t&3)*4; lane quads read contiguous 64B. Same st[] slots. ----
    {
#pragma unroll
        for (int p = 0; p < 4; ++p) {
            const int c = p * 64 + (tid >> 2), m4 = (tid & 3) * 4;
            float4 a = *(const float4*)&X[((long)c << 10) + mt16 * 16 + m4];
            float* d = &st[c * 17 + m4];
            d[0] = a.x; d[1] = a.y; d[2] = a.z; d[3] = a.w;
        }
    }

    const float* bias = (sel == 0 ? bq : sel == 1 ? bk : bv);
    float bbv[4][4];
#pragma unroll
    for (int i = 0; i < 4; ++i) {
        float4 b4 = *(const float4*)&bias[(wave * 4 + i) * 16 + quad * 4];
        bbv[i][0] = b4.x; bbv[i][1] = b4.y; bbv[i][2] = b4.z; bbv[i][3] = b4.w;
    }
    __syncthreads();

    floatx4 acc[4] = {{0.f,0.f,0.f,0.f},{0.f,0.f,0.f,0.f},
                      {0.f,0.f,0.f,0.f},{0.f,0.f,0.f,0.f}};
    const long abase = (long)sel * 65536 + (long)lane * 8;
#pragma unroll
    for (int kc = 0; kc < 8; ++kc) {
        short8 bh, bl;
        const float* col = &st[(kc * 32 + quad * 8) * 17 + n16];
#pragma unroll
        for (int j = 0; j < 8; ++j) {
            float f = col[j * 17];
            short hb = f2bf(f);
            bh[j] = hb;
            bl[j] = f2bf(f - bf2f(hb));
        }
#pragma unroll
        for (int i = 0; i < 4; ++i) {
            const int dt = wave * 4 + i;
            short8 ahi = *(const short8*)(Whi + abase + (long)(dt * 8 + kc) * 512);
            short8 alo = *(const short8*)(Wlo + abase + (long)(dt * 8 + kc) * 512);
            acc[i] = __builtin_amdgcn_mfma_f32_16x16x32_bf16(ahi, bh, acc[i], 0, 0, 0);
            acc[i] = __builtin_amdgcn_mfma_f32_16x16x32_bf16(ahi, bl, acc[i], 0, 0, 0);
            acc[i] = __builtin_amdgcn_mfma_f32_16x16x32_bf16(alo, bh, acc[i], 0, 0, 0);
        }
    }

    __syncthreads();
    float* tile = st;
#pragma unroll
    for (int i = 0; i < 4; ++i) {
        const int dt = wave * 4 + i;
#pragma unroll
        for (int r = 0; r < 4; ++r)
            tile[n16 * 257 + dt * 16 + quad * 4 + r] = acc[i][r] + bbv[i][r];
    }
    __syncthreads();

    if (sel == 2) {
        const int gg = tid >> 7, chp = tid & 127;
        const int yq = mt16 >> 1, xb = (mt16 & 1) * 16;
        short8 h0, h1, l0, l1;
#pragma unroll
        for (int j = 0; j < 8; ++j) {
            float f0 = tile[j * 257 + tid];
            float f1 = tile[(j + 8) * 257 + tid];
            short hb0 = f2bf(f0), hb1 = f2bf(f1);
            h0[j] = hb0; l0[j] = f2bf(f0 - bf2f(hb0));
            h1[j] = hb1; l1[j] = f2bf(f1 - bf2f(hb1));
        }
        long o = ((long)((batch * 2 + gg) * 128 + chp) * 32 + yq) * 48 + 8 + xb;
        *(short8*)(vhi + o) = h0;
        *(short8*)(vhi + o + 8) = h1;
        *(short8*)(vlo + o) = l0;
        *(short8*)(vlo + o + 8) = l1;
        const int prow = mt16 >> 1, side = mt16 & 1;
        long po = ((long)((batch * 2 + gg) * 128 + chp) * 32 + prow) * 48 + side * 40;
        short8 zz = {0,0,0,0,0,0,0,0};
        *(short8*)(vhi + po) = zz;
        *(short8*)(vlo + po) = zz;
        return;
    }

    const float scale = (sel == 1) ? 0.08838834764831845f : 1.0f;
    const int m_l = tid >> 4, c16 = (tid & 15) * 16;
    const int m = mt16 * 16 + m_l;
    short* oh = sel ? khi : qhi;
    short* ol = sel ? klo : qlo;
#pragma unroll
    for (int half = 0; half < 2; ++half) {
        const int cg = c16 + half * 8;
        short8 h8, l8;
#pragma unroll
        for (int j = 0; j < 8; ++j) {
            float f = tile[m_l * 257 + cg + j] * scale;
            short hb = f2bf(f);
            h8[j] = hb;
            l8[j] = f2bf(f - bf2f(hb));
        }
        const int g = cg >> 7, ch = cg & 127;
        const long base = (((long)(batch * 2 + g) << 10) + m) * 128 + ch;
        *(short8*)(oh + base) = h8;
        *(short8*)(ol + base) = l8;
    }
}

// ---------------------------------------------------------------------------
// scores_pv (round-14 verbatim): 512 px-tiles x 512 threads, M folded into R.
// ---------------------------------------------------------------------------
__global__ __launch_bounds__(512)
void scores_pv(const short* __restrict__ qhi, const short* __restrict__ qlo,
               const short* __restrict__ khi, const short* __restrict__ klo,
               const short* __restrict__ Wrh, const short* __restrict__ Wrl,
               const float* __restrict__ brel,
               const short* __restrict__ vhi, const short* __restrict__ vlo,
               const short* __restrict__ Vbh, const short* __restrict__ Vbl,
               short* __restrict__ AGhi, short* __restrict__ AGlo)
{
    __shared__ __align__(16) float qk[16 * 241];   // 15.4 KB; aliased as tile[16][133] in F
    __shared__ __align__(16) short pah[16 * 264];  // 8.25 KB
    __shared__ __align__(16) short pal[16 * 264];  // 8.25 KB
    __shared__ float invl[16];

    const int tid = threadIdx.x;
    const int wave = tid >> 6, lane = tid & 63;     // wave 0..7
    const int lin = blockIdx.x;
    const int bz  = lin & 7;
    const int yy  = lin >> 3;
    const int y   = yy >> 1;
    const int xt  = yy & 1;
    const int g = bz & 1;
    const int x0 = xt * 16;

    const int n16 = lane & 15, quad = lane >> 4;
    const long qbase = (((long)bz << 10) + y * 32 + x0 + n16) * 128 + quad * 8;
    short8 a_hi[4], a_lo[4];
#pragma unroll
    for (int ch = 0; ch < 4; ++ch) {
        a_hi[ch] = *(const short8*)(qhi + qbase + ch * 32);
        a_lo[ch] = *(const short8*)(qlo + qbase + ch * 32);
    }

    // ---- phase R: rel logits with inline boundary mask (M folded in) ----
    for (int wt = wave; wt < 15; wt += 8) {
        const short* Ah = Wrh + (long)g * 30720 + ((long)(wt * 4) * 64 + lane) * 8;
        const short* Al = Wrl + (long)g * 30720 + ((long)(wt * 4) * 64 + lane) * 8;
        floatx4 racc = {0.f, 0.f, 0.f, 0.f};
#pragma unroll
        for (int kc = 0; kc < 4; ++kc) {
            short8 whh = *(const short8*)(Ah + kc * 512);
            short8 wll = *(const short8*)(Al + kc * 512);
            racc = __builtin_amdgcn_mfma_f32_16x16x32_bf16(whh, a_hi[kc], racc, 0, 0, 0);
            racc = __builtin_amdgcn_mfma_f32_16x16x32_bf16(whh, a_lo[kc], racc, 0, 0, 0);
            racc = __builtin_amdgcn_mfma_f32_16x16x32_bf16(wll, a_hi[kc], racc, 0, 0, 0);
        }
#pragma unroll
        for (int r = 0; r < 4; ++r) {
            int w = wt * 16 + quad * 4 + r;
            if (w < 225) {
                int dy = w / 15, dx = w - dy * 15;
                int hy = y + dy - 7, hx = x0 + n16 + dx - 7;
                bool valid = (hy >= 0) && (hy < 32) && (hx >= 0) && (hx < 32);
                qk[n16 * 241 + dy * 16 + dx] =
                    valid ? (racc[r] + brel[g * 225 + w]) : -1e8f;
            }
        }
    }
    // pad slots (16 per px row: dy*16+15 and 240) -> -1e8
    if (tid < 256) {
        int px = tid >> 4, p = tid & 15;
        int slot = (p < 15) ? (p * 16 + 15) : 240;
        qk[px * 241 + slot] = -1e8f;
    }
    __syncthreads();

    // ---- phase B: band QK^T (15 dy over 8 waves) ----
    for (int dy = wave; dy < 15; dy += 8) {
        const int ky = y + dy - 7;
        if (ky < 0 || ky > 31) continue;
#pragma unroll
        for (int kxt = 0; kxt < 2; ++kxt) {
            const int kxg = x0 - 8 + kxt * 16 + n16;
            const long kb = (((long)bz << 10) + ky * 32 + kxg) * 128 + quad * 8;
            floatx4 acc = {0.f, 0.f, 0.f, 0.f};
#pragma unroll
            for (int ch = 0; ch < 4; ++ch) {
                short8 b_hi = *(const short8*)(khi + kb + ch * 32);
                short8 b_lo = *(const short8*)(klo + kb + ch * 32);
                acc = __builtin_amdgcn_mfma_f32_16x16x32_bf16(a_hi[ch], b_hi, acc, 0, 0, 0);
                acc = __builtin_amdgcn_mfma_f32_16x16x32_bf16(a_hi[ch], b_lo, acc, 0, 0, 0);
                acc = __builtin_amdgcn_mfma_f32_16x16x32_bf16(a_lo[ch], b_hi, acc, 0, 0, 0);
            }
            if (kxg >= 0 && kxg < 32) {
#pragma unroll
                for (int r = 0; r < 4; ++r) {
                    int m = quad * 4 + r;
                    int dx = kxg - (x0 + m) + 7;
                    if (dx >= 0 && dx < 15) {
                        int s = m * 241 + dy * 16 + dx;
                        qk[s] = qk[s] + acc[r];
                    }
                }
            }
        }
    }
    __syncthreads();

    // ---- softmax: 32 lanes per px row ----
    {
        int px = tid >> 5, s = tid & 31;
        float mx = -3.0e38f;
        for (int w = s; w < 240; w += 32) mx = fmaxf(mx, qk[px * 241 + w]);
#pragma unroll
        for (int msk = 16; msk; msk >>= 1) mx = fmaxf(mx, __shfl_xor(mx, msk));
        float sum = 0.f;
        for (int w = s; w < 240; w += 32) {
            float p = __expf(qk[px * 241 + w] - mx);
            qk[px * 241 + w] = p;
            sum += p;
        }
#pragma unroll
        for (int msk = 16; msk; msk >>= 1) sum += __shfl_xor(sum, msk);
        if (s == 0) invl[px] = 1.0f / sum;
    }
    __syncthreads();

    // ---- phase T: normalize + bf16 hi/lo into pah/pal (w >= 225 -> 0) ----
    for (int e = tid; e < 4096; e += 512) {
        int px = e >> 8, w = e & 255;
        float p = 0.f;
        if (w < 225) {
            int dy2 = w / 15, dx2 = w - dy2 * 15;
            p = qk[px * 241 + dy2 * 16 + dx2] * invl[px];
        }
        short hb = f2bf(p);
        pah[px * 264 + w] = hb;
        pal[px * 264 + w] = f2bf(p - bf2f(hb));
    }
    __syncthreads();

    // ---- phases A+V: MFMA accumulation, 1 ch-tile per wave (8 tiles) ----
    floatx4 acc = {0.f, 0.f, 0.f, 0.f};
    const int ch0 = wave * 16;

#pragma unroll
    for (int wk = 0; wk < 8; ++wk) {
        short8 pa_h = *(const short8*)&pah[n16 * 264 + wk * 32 + quad * 8];
        short8 pa_l = *(const short8*)&pal[n16 * 264 + wk * 32 + quad * 8];
        const long vb0 = (((long)(g * 128 + ch0 + n16)) << 8) + wk * 32 + quad * 8;
        short8 b0h = *(const short8*)(Vbh + vb0);
        short8 b0l = *(const short8*)(Vbl + vb0);
        acc = __builtin_amdgcn_mfma_f32_16x16x32_bf16(pa_h, b0h, acc, 0, 0, 0);
        acc = __builtin_amdgcn_mfma_f32_16x16x32_bf16(pa_h, b0l, acc, 0, 0, 0);
        acc = __builtin_amdgcn_mfma_f32_16x16x32_bf16(pa_l, b0h, acc, 0, 0, 0);
    }

    for (int dy = 0; dy < 15; ++dy) {
        const int ky = y + dy - 7;
        if (ky < 0 || ky > 31) continue;
        short8 bnd_h, bnd_l;
        const int rowoff = n16 * 264 + dy * 15 - n16 - 1;
#pragma unroll
        for (int j = 0; j < 8; ++j) {
            int kk = quad * 8 + j;
            int dx = kk - n16 - 1;
            bool valid = (unsigned)dx < 15u;
            int idx = valid ? (rowoff + kk) : 0;
            short vh = pah[idx];
            short vl = pal[idx];
            bnd_h[j] = valid ? vh : (short)0;
            bnd_l[j] = valid ? vl : (short)0;
        }
        const long v0o = (((long)((bz * 128 + ch0 + n16)) * 32 + ky)) * 48 + x0 + quad * 8;
        short8 v0h = *(const short8*)(vhi + v0o);
        short8 v0l = *(const short8*)(vlo + v0o);
        acc = __builtin_amdgcn_mfma_f32_16x16x32_bf16(bnd_h, v0h, acc, 0, 0, 0);
        acc = __builtin_amdgcn_mfma_f32_16x16x32_bf16(bnd_h, v0l, acc, 0, 0, 0);
        acc = __builtin_amdgcn_mfma_f32_16x16x32_bf16(bnd_l, v0h, acc, 0, 0, 0);
    }

    // ---- phase F: stage tile [16 px][128 ch] then AG frag conversion ----
    float* tile = qk;                    // [16][133]
    {
        const int cb = ch0 + n16;
#pragma unroll
        for (int r = 0; r < 4; ++r)
            tile[(quad * 4 + r) * 133 + cb] = acc[r];
    }
    __syncthreads();

    const int sub = tid >> 6;
    if (sub < 4) {
        short8 h8, l8;
#pragma unroll
        for (int j = 0; j < 8; ++j) {
            float f = tile[n16 * 133 + sub * 32 + quad * 8 + j];
            short hb = f2bf(f);
            h8[j] = hb;
            l8[j] = f2bf(f - bf2f(hb));
        }
        const int n = bz >> 1;
        const int mt16 = y * 2 + xt;
        const int kc = g * 4 + sub;
        long off = (long)n * 262144 + (((long)(mt16 * 8 + kc) * 64) + lane) * 8;
        *(short8*)(AGhi + off) = h8;
        *(short8*)(AGlo + off) = l8;
    }
}

// ---------------------------------------------------------------------------
// mfma_fc v2 (verbatim): grid (mt16 64, db 4, nz 4) = 1024 blocks.
// ---------------------------------------------------------------------------
__global__ __launch_bounds__(256)
void mfma_fc(const short* __restrict__ Ahi, const short* __restrict__ Alo,
             const short* __restrict__ Whi, const short* __restrict__ Wlo,
             const float* __restrict__ bfc, float* __restrict__ out)
{
    __shared__ float tile[16 * 68];
    const int tid = threadIdx.x;
    const int wave = tid >> 6, lane = tid & 63;
    const int n16 = lane & 15, quad = lane >> 4;
    const int mt16 = blockIdx.x, db = blockIdx.y, nz = blockIdx.z;
    const int dt = db * 4 + wave;

    const short* Ah = Whi + (long)3 * 65536 + ((long)(dt * 8) * 64 + lane) * 8;
    const short* Al = Wlo + (long)3 * 65536 + ((long)(dt * 8) * 64 + lane) * 8;
    const short* Bh = Ahi + (long)nz * 262144;
    const short* Bl = Alo + (long)nz * 262144;

    float4 bv4 = *(const float4*)&bfc[dt * 16 + quad * 4];
    float bb[4] = {bv4.x, bv4.y, bv4.z, bv4.w};

    floatx4 acc = {0.f, 0.f, 0.f, 0.f};
#pragma unroll
    for (int kc = 0; kc < 8; ++kc) {
        short8 ahi = *(const short8*)(Ah + kc * 512);
        short8 alo = *(const short8*)(Al + kc * 512);
        long bo = ((long)(mt16 * 8 + kc) * 64 + lane) * 8;
        short8 bh = *(const short8*)(Bh + bo);
        short8 bl = *(const short8*)(Bl + bo);
        acc = __builtin_amdgcn_mfma_f32_16x16x32_bf16(ahi, bh, acc, 0, 0, 0);
        acc = __builtin_amdgcn_mfma_f32_16x16x32_bf16(ahi, bl, acc, 0, 0, 0);
        acc = __builtin_amdgcn_mfma_f32_16x16x32_bf16(alo, bh, acc, 0, 0, 0);
    }

    const int dl = wave * 16 + quad * 4;
#pragma unroll
    for (int r = 0; r < 4; ++r)
        tile[n16 * 68 + dl + r] = acc[r] + bb[r];
    __syncthreads();

    const int mm = tid >> 4, d4 = (tid & 15) * 4;
    float4 o4 = *(const float4*)&tile[mm * 68 + d4];
    *(float4*)&out[(long)(mt16 * 16 + mm) * 1024 + nz * 256 + db * 64 + d4] = o4;
}

// ---------------------------------------------------------------------------
// ws floats:
//   vhi@2097152 (786432 fl as shorts) vlo@2883584
//   Vbh@4718592 (32768 fl) Vbl@4751360
//   qhi@6561792 qlo@7086080 khi@7610368 klo@8134656 (524288 each)
//   Whi@11804672 (131072, 4 sels) Wlo@11935744
//   AGhi@12066816 (524288) AGlo@12591104
//   Wrh@13115392 (30720) Wrl@13146112
// ---------------------------------------------------------------------------
extern "C" void kernel_launch(void* const* d_in, const int* in_sizes, int n_in,
                              void* d_out, int out_size, void* d_ws, size_t ws_size,
                              hipStream_t stream)
{
    const float* q    = (const float*)d_in[0];
    const float* k    = (const float*)d_in[1];
    const float* v    = (const float*)d_in[2];
    const float* Wq   = (const float*)d_in[3];
    const float* bq   = (const float*)d_in[4];
    const float* Wk   = (const float*)d_in[5];
    const float* bk   = (const float*)d_in[6];
    const float* Wv   = (const float*)d_in[7];
    const float* bv   = (const float*)d_in[8];
    const float* Wrel = (const float*)d_in[9];
    const float* brel = (const float*)d_in[10];
    const float* Vb   = (const float*)d_in[11];
    const float* Wfc  = (const float*)d_in[12];
    const float* bfc  = (const float*)d_in[13];
    float* out = (float*)d_out;

    float* ws   = (float*)d_ws;
    short* vhi  = (short*)(ws + 2097152);
    short* vlo  = (short*)(ws + 2883584);
    short* Vbh  = (short*)(ws + 4718592);
    short* Vbl  = (short*)(ws + 4751360);
    short* qhi  = (short*)(ws + 6561792);
    short* qlo  = (short*)(ws + 7086080);
    short* khi  = (short*)(ws + 7610368);
    short* klo  = (short*)(ws + 8134656);
    short* Whi  = (short*)(ws + 11804672);
    short* Wlo  = (short*)(ws + 11935744);
    short* AGhi = (short*)(ws + 12066816);
    short* AGlo = (short*)(ws + 12591104);
    short* Wrh  = (short*)(ws + 13115392);
    short* Wrl  = (short*)(ws + 13146112);

    // Wq/Wk/Wv A-frags only (gates proj): 96 blocks
    prep<<<dim3(96), dim3(256), 0, stream>>>(Wq, Wk, Wv, Whi, Wlo);

    // QKV projections (coalesced staging) + constants (z==12): 832 blocks
    mfma_proj<<<dim3(64, 13), dim3(256), 0, stream>>>(q, k, v, Wfc, Wrel, Vb,
                                                      Whi, Wlo,
                                                      bq, bk, bv,
                                                      qhi, qlo, khi, klo,
                                                      vhi, vlo,
                                                      Wrh, Wrl, Vbh, Vbl);

    // rel(+mask) + band QK^T + softmax + MFMA PV -> AG frags: 512 x 512
    scores_pv<<<dim3(512), dim3(512), 0, stream>>>(qhi, qlo, khi, klo,
                                                   Wrh, Wrl, brel,
                                                   vhi, vlo, Vbh, Vbl,
                                                   AGhi, AGlo);

    // FC via MFMA: 1024 blocks (4/CU)
    mfma_fc<<<dim3(64, 4, 4), dim3(256), 0, stream>>>(AGhi, AGlo, Whi, Wlo,
                                                      bfc, out);
}